// Round 12
// baseline (443.511 us; speedup 1.0000x reference)
//
#include <hip/hip_runtime.h>
#include <stdint.h>
#include <math.h>

// ---------------------------------------------------------------------------
// BitAttention: B=2, T=2048, D=2048, H=16, HD=128
//   q/k/v = int4-quant(x) @ ternary(w)^T   (exact int math via i8 MFMA)
//   RoPE + K/V f16-split fused into GEMM epilogue, K/V stored in MFMA
//   FRAGMENT ORDER; flash attention is LDS-free and barrier-free (coalesced
//   wave-level fragment loads from L1/L2), f16 hi/lo 3-term split, defer-max,
//   permlane32_swap repack, setprio.
//   out = int8-quant(topk_0.55(attn)) @ ternary(wo)^T (exact int via i8 MFMA)
// ---------------------------------------------------------------------------

typedef __attribute__((ext_vector_type(8))) short short8;
typedef __attribute__((ext_vector_type(4))) int i32x4;
typedef __attribute__((ext_vector_type(8))) _Float16 f16x8;
typedef __attribute__((ext_vector_type(16))) float f32x16;

#define GLDS16(g, l)                                                        \
  __builtin_amdgcn_global_load_lds(                                         \
      (const __attribute__((address_space(1))) void*)(g),                   \
      (__attribute__((address_space(3))) void*)(l), 16, 0, 0)

__device__ __forceinline__ unsigned short f2bf(float v) {
  return (unsigned short)(__float_as_uint(v) >> 16);
}

// ---------------- cos/sin tables (T x 64), faithful f32 path ---------------
__global__ __launch_bounds__(256) void k_costab(float* __restrict__ ct,
                                                float* __restrict__ st) {
  int idx = blockIdx.x * 256 + threadIdx.x;  // 2048*64
  int t = idx >> 6, i = idx & 63;
  float f = (float)(2 * i) / 128.0f;
  float inv = 1.0f / powf(10000.0f, f);
  float fr = (float)t * inv;
  ct[idx] = cosf(fr);
  st[idx] = sinf(fr);
}

// ---------------- weight scale: mean(|w|), deterministic f64 tree ----------
__global__ __launch_bounds__(256) void k_wsum(const float* __restrict__ w0,
                                              const float* __restrict__ w1,
                                              const float* __restrict__ w2,
                                              const float* __restrict__ w3,
                                              double* __restrict__ part) {
  int bx = blockIdx.x;  // 0..4095 ; 1024 blocks per matrix
  int mat = bx >> 10;
  const float* w = (mat == 0) ? w0 : (mat == 1) ? w1 : (mat == 2) ? w2 : w3;
  int base = (bx & 1023) * 4096;
  double s = 0.0;
#pragma unroll
  for (int i = 0; i < 16; ++i)
    s += (double)fabsf(w[base + threadIdx.x + i * 256]);
  __shared__ double red[256];
  red[threadIdx.x] = s;
  __syncthreads();
  for (int off = 128; off; off >>= 1) {
    if (threadIdx.x < off) red[threadIdx.x] += red[threadIdx.x + off];
    __syncthreads();
  }
  if (threadIdx.x == 0) part[bx] = red[0];
}

__global__ __launch_bounds__(256) void k_wscale(const double* __restrict__ part,
                                                float* __restrict__ wsc) {
  int m = blockIdx.x, tid = threadIdx.x;
  const double* p = part + m * 1024;
  double s = p[tid] + p[tid + 256] + p[tid + 512] + p[tid + 768];
  __shared__ double red[256];
  red[tid] = s;
  __syncthreads();
  for (int off = 128; off; off >>= 1) {
    if (tid < off) red[tid] += red[tid + off];
    __syncthreads();
  }
  if (tid == 0) wsc[m] = (float)(red[0] / 4194304.0);
}

// ---------------- ternary quantize weights -> int8 {-1,0,1} ----------------
__global__ __launch_bounds__(256) void k_wquant(const float* __restrict__ w0,
                                                const float* __restrict__ w1,
                                                const float* __restrict__ w2,
                                                const float* __restrict__ w3,
                                                const float* __restrict__ wsc,
                                                signed char* __restrict__ wt) {
  int mat = blockIdx.y;
  const float* w = (mat == 0) ? w0 : (mat == 1) ? w1 : (mat == 2) ? w2 : w3;
  float se = wsc[mat] + 1e-5f;
  size_t base = (size_t)blockIdx.x * 4096;
  signed char* o = wt + (size_t)mat * 4194304 + base;
  const float* wp = w + base;
#pragma unroll 4
  for (int i = 0; i < 16; ++i) {
    int idx = threadIdx.x + i * 256;
    float v = rintf(wp[idx] / se);
    v = fminf(fmaxf(v, -1.0f), 1.0f);
    o[idx] = (signed char)v;
  }
}

// ---------------- int4 row-quantize x -> int8 + 1/s scale ------------------
__global__ __launch_bounds__(256) void k_xquant(const float* __restrict__ x,
                                                signed char* __restrict__ xq,
                                                float* __restrict__ sx) {
  int row = blockIdx.x, tid = threadIdx.x;
  const float* xr = x + (size_t)row * 2048;
  float v[8];
  float mx = 0.0f;
#pragma unroll
  for (int i = 0; i < 8; ++i) {
    v[i] = xr[tid + i * 256];
    mx = fmaxf(mx, fabsf(v[i]));
  }
  __shared__ float red[256];
  red[tid] = mx;
  __syncthreads();
  for (int off = 128; off; off >>= 1) {
    if (tid < off) red[tid] = fmaxf(red[tid], red[tid + off]);
    __syncthreads();
  }
  float s = 7.0f / fmaxf(red[0], 1e-5f);
#pragma unroll
  for (int i = 0; i < 8; ++i) {
    float q = rintf(v[i] * s);
    q = fminf(fmaxf(q, -8.0f), 7.0f);
    xq[(size_t)row * 2048 + tid + i * 256] = (signed char)q;
  }
  if (tid == 0) sx[row] = s;
}

// ---------------- fused QKV i8 GEMM + RoPE / frag-layout epilogues ---------
// mat 0 (Q): rope, f32 qb.
// mat 1 (K): rope, f16 hi/lo split, stored in QK A-fragment order:
//   kf[((bh*64+kt)*8 + ds)*512 + (hi*32+rl)*8 + i] = K[t=kt*32+rl][ds*16+hi*8+i]
// mat 2 (V): LDS transpose (granule-XOR swizzle) then PV B-fragment order:
//   vf[((bh*64+kt)*8 + df*2+hf)*512 + (hi*32+rl)*8 + i]
//     = V[t=kt*32+(2hf+hi)*8+i][df*32+rl]
__global__ __launch_bounds__(256) void k_gemm3(const signed char* __restrict__ A,
                                               const signed char* __restrict__ wtall,
                                               float* __restrict__ qo,
                                               _Float16* __restrict__ kfh,
                                               _Float16* __restrict__ kfl,
                                               _Float16* __restrict__ vfh,
                                               _Float16* __restrict__ vfl,
                                               const float* __restrict__ srow,
                                               const float* __restrict__ wsc,
                                               const float* __restrict__ ct,
                                               const float* __restrict__ st) {
  __shared__ alignas(16) signed char As[128 * 64];
  __shared__ alignas(16) signed char Bs[128 * 64];
  __shared__ float fac[128];
  const int tid = threadIdx.x, wave = tid >> 6, lane = tid & 63;
  const int bxi = blockIdx.x;
  const int mat = bxi >> 4;
  const signed char* Bw = wtall + (size_t)mat * 4194304;
  const int brow = blockIdx.y * 128, bcol = (bxi & 15) * 128;
  if (tid < 128) fac[tid] = wsc[mat] / srow[brow + tid];
  const int wr = wave >> 1, wc = wave & 1;
  i32x4 acc[4][4];
#pragma unroll
  for (int m = 0; m < 4; ++m)
#pragma unroll
    for (int n = 0; n < 4; ++n) acc[m][n] = (i32x4){0, 0, 0, 0};
  const int srl = tid >> 2;                            // staged row 0..63
  const int ssw = ((tid & 3) ^ ((srl >> 1) & 3)) * 16; // swizzled k-offset
  const signed char* Ag = A + (size_t)(brow + srl) * 2048 + ssw;
  const signed char* Bg = Bw + (size_t)(bcol + srl) * 2048 + ssw;
  char* AsB = (char*)As + wave * 1024;
  char* BsB = (char*)Bs + wave * 1024;
  const int fr = lane & 15, kb = lane >> 4;
  const int rsl = (kb ^ ((fr >> 1) & 3)) * 16;  // swizzled read slot
  for (int k0 = 0; k0 < 2048; k0 += 64) {
    __syncthreads();
    GLDS16(Ag + k0, AsB);
    GLDS16(Ag + k0 + (size_t)64 * 2048, AsB + 4096);
    GLDS16(Bg + k0, BsB);
    GLDS16(Bg + k0 + (size_t)64 * 2048, BsB + 4096);
    __syncthreads();
    i32x4 af[4], bf[4];
#pragma unroll
    for (int m = 0; m < 4; ++m)
      af[m] = *(const i32x4*)&As[(wr * 64 + m * 16 + fr) * 64 + rsl];
#pragma unroll
    for (int n = 0; n < 4; ++n)
      bf[n] = *(const i32x4*)
           &Bs[(wc * 32 + (n & 1) * 16 + (n >> 1) * 64 + fr) * 64 + rsl];
#pragma unroll
    for (int m = 0; m < 4; ++m)
#pragma unroll
      for (int n = 0; n < 4; ++n)
        acc[m][n] = __builtin_amdgcn_mfma_i32_16x16x64_i8(af[m], bf[n],
                                                          acc[m][n], 0, 0, 0);
  }
  const int fq = lane >> 4;
  const int hh = bcol >> 7;  // head index
  const int bb0 = brow >> 11, tbase = brow & 2047;
  const int bh = bb0 * 16 + hh;
  if (mat == 2) {
    // ---- V: LDS transpose quarters (granule-XOR) -> fragment-order dump ----
    _Float16* Ah = (_Float16*)As;  // [32 d][128 t] hi plane, swizzled granules
    _Float16* Al = (_Float16*)Bs;  // lo plane
#pragma unroll
    for (int q = 0; q < 4; ++q) {
      __syncthreads();  // LDS free
      if (wc == (q & 1)) {
#pragma unroll
        for (int m = 0; m < 4; ++m)
#pragma unroll
          for (int nn = 0; nn < 2; ++nn) {
            int n = (q >> 1) * 2 + nn;
            int dl = nn * 16 + fr;
#pragma unroll
            for (int r = 0; r < 4; ++r) {
              int tl = wr * 64 + m * 16 + fq * 4 + r;
              float val = (float)acc[m][n][r] * fac[tl];
              _Float16 hv = (_Float16)val;
              int col = ((((tl >> 3) ^ (dl & 15)) << 3) | (tl & 7));
              Ah[dl * 128 + col] = hv;
              Al[dl * 128 + col] = (_Float16)(val - (float)hv);
            }
          }
      }
      __syncthreads();
      {  // dump quarter q (df=q) in fragment order; coalesced 16B stores
        int ktl = tid >> 6, l = tid & 63;
        int rrl = l & 31, hhi = l >> 5;
#pragma unroll
        for (int hf = 0; hf < 2; ++hf) {
          int gi = ktl * 4 + 2 * hf + hhi;
          int gp = gi ^ (rrl & 15);
          f16x8 vh = *(const f16x8*)&Ah[rrl * 128 + gp * 8];
          f16x8 vl = *(const f16x8*)&Al[rrl * 128 + gp * 8];
          int ktg = (tbase >> 5) + ktl;
          size_t fb = (((size_t)bh * 64 + ktg) * 8 + q * 2 + hf) * 512 + l * 8;
          *(f16x8*)(vfh + fb) = vh;
          *(f16x8*)(vfl + fb) = vl;
        }
      }
    }
  } else {
#pragma unroll
    for (int m = 0; m < 4; ++m)
#pragma unroll
      for (int n = 0; n < 2; ++n) {
        int d1 = wc * 32 + n * 16 + fr;  // [0,64)
#pragma unroll
        for (int r = 0; r < 4; ++r) {
          int row = wr * 64 + m * 16 + fq * 4 + r;
          int rg = brow + row;
          int t = rg & 2047;
          float c = ct[t * 64 + d1], sn = st[t * 64 + d1];
          float x1 = (float)acc[m][n][r] * fac[row];
          float x2 = (float)acc[m][n + 2][r] * fac[row];
          float y1 = x1 * c - x2 * sn;
          float y2 = x2 * c + x1 * sn;
          if (mat == 0) {
            qo[(size_t)rg * 2048 + bcol + d1] = y1;
            qo[(size_t)rg * 2048 + bcol + d1 + 64] = y2;
          } else {
            // K fragment-order write (2B scatters, same count as before)
            int kt = t >> 5, rl2 = t & 31;
            int ds1 = wc * 2 + n;
            int hii = fr >> 3, ii = fr & 7;
            size_t fb = ((size_t)bh * 64 + kt) * 4096;
            size_t a1 = fb + (size_t)ds1 * 512 + (hii * 32 + rl2) * 8 + ii;
            size_t a2 = fb + (size_t)(ds1 + 4) * 512 + (hii * 32 + rl2) * 8 + ii;
            _Float16 h1 = (_Float16)y1, h2 = (_Float16)y2;
            kfh[a1] = h1;
            kfl[a1] = (_Float16)(y1 - (float)h1);
            kfh[a2] = h2;
            kfl[a2] = (_Float16)(y2 - (float)h2);
          }
        }
      }
  }
}

// ---------------- single i8 GEMM (output projection) -----------------------
__global__ __launch_bounds__(256) void k_gemm(const signed char* __restrict__ A,
                                              const signed char* __restrict__ Bw,
                                              float* __restrict__ C,
                                              const float* __restrict__ srow,
                                              const float* __restrict__ wsp) {
  __shared__ alignas(16) signed char As[128 * 64];
  __shared__ alignas(16) signed char Bs[128 * 64];
  __shared__ float fac[128];
  const int tid = threadIdx.x, wave = tid >> 6, lane = tid & 63;
  const int brow = blockIdx.y * 128, bcol = blockIdx.x * 128;
  if (tid < 128) fac[tid] = wsp[0] / srow[brow + tid];
  const int wr = wave >> 1, wc = wave & 1;
  i32x4 acc[4][4];
#pragma unroll
  for (int m = 0; m < 4; ++m)
#pragma unroll
    for (int n = 0; n < 4; ++n) acc[m][n] = (i32x4){0, 0, 0, 0};
  const int srl = tid >> 2;
  const int ssw = ((tid & 3) ^ ((srl >> 1) & 3)) * 16;
  const signed char* Ag = A + (size_t)(brow + srl) * 2048 + ssw;
  const signed char* Bg = Bw + (size_t)(bcol + srl) * 2048 + ssw;
  char* AsB = (char*)As + wave * 1024;
  char* BsB = (char*)Bs + wave * 1024;
  const int fr = lane & 15, kb = lane >> 4;
  const int rsl = (kb ^ ((fr >> 1) & 3)) * 16;
  for (int k0 = 0; k0 < 2048; k0 += 64) {
    __syncthreads();
    GLDS16(Ag + k0, AsB);
    GLDS16(Ag + k0 + (size_t)64 * 2048, AsB + 4096);
    GLDS16(Bg + k0, BsB);
    GLDS16(Bg + k0 + (size_t)64 * 2048, BsB + 4096);
    __syncthreads();
    i32x4 af[4], bf[4];
#pragma unroll
    for (int m = 0; m < 4; ++m)
      af[m] = *(const i32x4*)&As[(wr * 64 + m * 16 + fr) * 64 + rsl];
#pragma unroll
    for (int n = 0; n < 4; ++n)
      bf[n] = *(const i32x4*)&Bs[(wc * 64 + n * 16 + fr) * 64 + rsl];
#pragma unroll
    for (int m = 0; m < 4; ++m)
#pragma unroll
      for (int n = 0; n < 4; ++n)
        acc[m][n] = __builtin_amdgcn_mfma_i32_16x16x64_i8(af[m], bf[n],
                                                          acc[m][n], 0, 0, 0);
  }
  const int fq = lane >> 4;
#pragma unroll
  for (int m = 0; m < 4; ++m)
#pragma unroll
    for (int n = 0; n < 4; ++n)
#pragma unroll
      for (int r = 0; r < 4; ++r) {
        int row = wr * 64 + m * 16 + fq * 4 + r;
        C[(size_t)(brow + row) * 2048 + bcol + wc * 64 + n * 16 + fr] =
            (float)acc[m][n][r] * fac[row];
      }
}

// ---------------- MFMA flash attention: LDS-free, barrier-free -------------
// 4 independent waves, 128 q rows/block. K-tile 32, 32x32x16 f16 MFMAs,
// hi/lo 3-term split. Fragments pre-laid-out in global memory; each frag
// load = one coalesced wave dwordx4 (lane*16B). All 4 waves read identical
// lines (L1 broadcast); 16 blocks/bh share 2MB frag data (L2-resident).
// exp2-domain softmax, defer-max, permlane32_swap repack, setprio.
__global__ __launch_bounds__(256, 2) void k_attn(float* __restrict__ qb,
                                                 const _Float16* __restrict__ kfh,
                                                 const _Float16* __restrict__ kfl,
                                                 const _Float16* __restrict__ vfh,
                                                 const _Float16* __restrict__ vfl) {
  const int tid = threadIdx.x;
  const int wave = tid >> 6, lane = tid & 63;
  const int rl = lane & 31, hi = lane >> 5, hi8 = hi * 8;
  const int bid = blockIdx.x;
  const int xcd = bid & 7, li = bid >> 3;            // XCD-aware: 4 bh per XCD
  const int bh = xcd * 4 + (li >> 4), qt = li & 15;  // bh-coherent chunks of 16
  const int b = bh >> 4, h = bh & 15;
  const size_t rowbase = (size_t)b * 2048;
  const int hcol = h * 128;
  const float F = 0.08838834764831845f * 1.44269504088896f;  // SCALE*log2e
  const float THR = 11.5415603f;                             // 8*log2e

  // ---- Q fragments (hi/lo f16, SCALE*log2e prefolded) ----
  f16x8 qh[8], ql[8];
  {
    const float* qsrc =
        qb + (rowbase + qt * 128 + wave * 32 + rl) * 2048 + hcol + hi8;
#pragma unroll
    for (int ds = 0; ds < 8; ++ds) {
      float4 a = *(const float4*)(qsrc + ds * 16);
      float4 c = *(const float4*)(qsrc + ds * 16 + 4);
      float v[8] = {a.x, a.y, a.z, a.w, c.x, c.y, c.z, c.w};
      f16x8 hh, ll;
#pragma unroll
      for (int i = 0; i < 8; ++i) {
        float sv = v[i] * F;
        _Float16 hv = (_Float16)sv;
        hh[i] = hv;
        ll[i] = (_Float16)(sv - (float)hv);
      }
      qh[ds] = hh;
      ql[ds] = ll;
    }
  }

  // per-lane fragment stream bases (coalesced: lane*16B within each 1KB frag)
  const _Float16* kbh = kfh + (size_t)bh * 262144 + lane * 8;
  const _Float16* kbl = kfl + (size_t)bh * 262144 + lane * 8;
  const _Float16* vbh = vfh + (size_t)bh * 262144 + lane * 8;
  const _Float16* vbl = vfl + (size_t)bh * 262144 + lane * 8;

  f32x16 Oa[4];
#pragma unroll
  for (int df = 0; df < 4; ++df)
#pragma unroll
    for (int i = 0; i < 16; ++i) Oa[df][i] = 0.0f;
  float m = -INFINITY, lsum = 0.0f;

  for (int kt = 0; kt < 64; ++kt) {
    const size_t tb = (size_t)kt * 4096;
    // ---- K fragment loads (16 coalesced dwordx4, all in flight) ----
    f16x8 ah[8], al[8];
#pragma unroll
    for (int ds = 0; ds < 8; ++ds) {
      ah[ds] = *(const f16x8*)(kbh + tb + ds * 512);
      al[ds] = *(const f16x8*)(kbl + tb + ds * 512);
    }
    // ---- QK: 3 independent chains ----
    f32x16 sA = {}, sB = {}, sC = {};
    __builtin_amdgcn_s_setprio(1);
#pragma unroll
    for (int ds = 0; ds < 8; ++ds) {
      sA = __builtin_amdgcn_mfma_f32_32x32x16_f16(ah[ds], qh[ds], sA, 0, 0, 0);
      sB = __builtin_amdgcn_mfma_f32_32x32x16_f16(ah[ds], ql[ds], sB, 0, 0, 0);
      sC = __builtin_amdgcn_mfma_f32_32x32x16_f16(al[ds], qh[ds], sC, 0, 0, 0);
    }
    __builtin_amdgcn_s_setprio(0);
    // ---- V fragment loads issued now; latency hides under QK drain/softmax
    f16x8 wh[8], wl[8];
#pragma unroll
    for (int j = 0; j < 8; ++j) {
      wh[j] = *(const f16x8*)(vbh + tb + j * 512);
      wl[j] = *(const f16x8*)(vbl + tb + j * 512);
    }
    // ---- merge chains ----
    f32x16 s;
#pragma unroll
    for (int i = 0; i < 16; ++i) s[i] = (sA[i] + sB[i]) + sC[i];
    // ---- online softmax (exp2 domain), defer-max ----
    float pm = fmaxf(
        fmaxf(fmaxf(fmaxf(s[0], s[1]), fmaxf(s[2], s[3])),
              fmaxf(fmaxf(s[4], s[5]), fmaxf(s[6], s[7]))),
        fmaxf(fmaxf(fmaxf(s[8], s[9]), fmaxf(s[10], s[11])),
              fmaxf(fmaxf(s[12], s[13]), fmaxf(s[14], s[15]))));
    pm = fmaxf(pm, __shfl_xor(pm, 32));
    float alpha = 1.0f;
    if (__any(pm > m + THR)) {  // rare after tile 0
      float mn = fmaxf(m, pm);
      alpha = exp2f(m - mn);  // m=-inf -> 0
      m = mn;
#pragma unroll
      for (int reg = 0; reg < 16; ++reg) {
        int qr = (reg & 3) + 8 * (reg >> 2) + 4 * hi;
        float av = __shfl(alpha, qr);
        Oa[0][reg] *= av;
        Oa[1][reg] *= av;
        Oa[2][reg] *= av;
        Oa[3][reg] *= av;
      }
    }
    unsigned int pkhh[4][2], pkll[4][2];
    float ls = 0.0f;
#pragma unroll
    for (int t4 = 0; t4 < 4; ++t4)
#pragma unroll
      for (int c2 = 0; c2 < 2; ++c2) {
        float pa = exp2f(s[4 * t4 + 2 * c2] - m);
        float pb = exp2f(s[4 * t4 + 2 * c2 + 1] - m);
        ls += pa + pb;
        auto hp = __builtin_amdgcn_cvt_pkrtz(pa, pb);
        float la = pa - (float)hp[0], lb = pb - (float)hp[1];
        auto lp = __builtin_amdgcn_cvt_pkrtz(la, lb);
        pkhh[t4][c2] = __builtin_bit_cast(unsigned int, hp);
        pkll[t4][c2] = __builtin_bit_cast(unsigned int, lp);
      }
    ls += __shfl_xor(ls, 32);
    lsum = lsum * alpha + ls;
    // ---- repack P -> PV A-frags via permlane32_swap ----
    f16x8 paH[2], paL[2];
#pragma unroll
    for (int hf = 0; hf < 2; ++hf) {
      {
        unsigned int a0 = pkhh[2 * hf][0], b0 = pkhh[2 * hf + 1][0];
        unsigned int a1 = pkhh[2 * hf][1], b1 = pkhh[2 * hf + 1][1];
        asm("v_permlane32_swap_b32 %0, %1" : "+v"(a0), "+v"(b0));
        asm("v_permlane32_swap_b32 %0, %1" : "+v"(a1), "+v"(b1));
        uint4 u;
        u.x = a0; u.y = a1; u.z = b0; u.w = b1;
        paH[hf] = __builtin_bit_cast(f16x8, u);
      }
      {
        unsigned int a0 = pkll[2 * hf][0], b0 = pkll[2 * hf + 1][0];
        unsigned int a1 = pkll[2 * hf][1], b1 = pkll[2 * hf + 1][1];
        asm("v_permlane32_swap_b32 %0, %1" : "+v"(a0), "+v"(b0));
        asm("v_permlane32_swap_b32 %0, %1" : "+v"(a1), "+v"(b1));
        uint4 u;
        u.x = a0; u.y = a1; u.z = b0; u.w = b1;
        paL[hf] = __builtin_bit_cast(f16x8, u);
      }
    }
    // ---- PV: O += P @ V (3-term split, 4 independent chains) ----
    __builtin_amdgcn_s_setprio(1);
#pragma unroll
    for (int df = 0; df < 4; ++df) {
#pragma unroll
      for (int hf = 0; hf < 2; ++hf) {
        const int j = df * 2 + hf;
        Oa[df] = __builtin_amdgcn_mfma_f32_32x32x16_f16(paH[hf], wh[j], Oa[df], 0, 0, 0);
        Oa[df] = __builtin_amdgcn_mfma_f32_32x32x16_f16(paH[hf], wl[j], Oa[df], 0, 0, 0);
        Oa[df] = __builtin_amdgcn_mfma_f32_32x32x16_f16(paL[hf], wh[j], Oa[df], 0, 0, 0);
      }
    }
    __builtin_amdgcn_s_setprio(0);
  }
  // ---- normalize + store in-place into our own q rows ----
  float linv = 1.0f / lsum;
  float* obase = qb + (rowbase + qt * 128 + wave * 32) * 2048 + hcol;
#pragma unroll
  for (int reg = 0; reg < 16; ++reg) {
    int qr = (reg & 3) + 8 * (reg >> 2) + 4 * hi;
    float lv = __shfl(linv, qr);
    float* orow = obase + (size_t)qr * 2048;
    orow[0 * 32 + rl] = Oa[0][reg] * lv;
    orow[1 * 32 + rl] = Oa[1][reg] * lv;
    orow[2 * 32 + rl] = Oa[2][reg] * lv;
    orow[3 * 32 + rl] = Oa[3][reg] * lv;
  }
}

// ---------------- topk(0.55)+int8 quantize per row (exact tie handling) ----
__global__ __launch_bounds__(256) void k_topk(const float* __restrict__ ain,
                                              signed char* __restrict__ oq,
                                              float* __restrict__ so) {
  const int row = blockIdx.x, tid = threadIdx.x;
  const float* xr = ain + (size_t)row * 2048;
  __shared__ unsigned int bits[2048];
  __shared__ unsigned int hist[256];
  __shared__ unsigned int scn[256];
  __shared__ unsigned int stat[3];  // prefix, rk, maxbits
#pragma unroll
  for (int j = 0; j < 8; ++j) {
    int i = tid * 8 + j;
    bits[i] = __float_as_uint(xr[i]) & 0x7fffffffu;
  }
  unsigned int mx = 0;
#pragma unroll
  for (int j = 0; j < 8; ++j) mx = max(mx, bits[tid * 8 + j]);
  scn[tid] = mx;
  __syncthreads();
  for (int off = 128; off; off >>= 1) {
    if (tid < off) scn[tid] = max(scn[tid], scn[tid + off]);
    __syncthreads();
  }
  if (tid == 0) { stat[0] = 0u; stat[1] = 1126u; stat[2] = scn[0]; }
  for (int p = 0; p < 4; ++p) {
    const int shift = 24 - 8 * p;
    hist[tid] = 0u;
    __syncthreads();
    unsigned int pref = stat[0];
    unsigned int rk0 = stat[1];
#pragma unroll
    for (int j = 0; j < 8; ++j) {
      unsigned int u = bits[tid * 8 + j];
      bool match = (p == 0) || ((u >> (shift + 8)) == pref);
      if (match) atomicAdd(&hist[(u >> shift) & 255u], 1u);
    }
    __syncthreads();
    scn[tid] = hist[tid];
    __syncthreads();
    for (int off = 1; off < 256; off <<= 1) {
      unsigned int v = (tid + off < 256) ? scn[tid + off] : 0u;
      __syncthreads();
      scn[tid] += v;
      __syncthreads();
    }
    unsigned int nxt = (tid == 255) ? 0u : scn[tid + 1];
    if (scn[tid] >= rk0 && nxt < rk0) {
      stat[0] = (pref << 8) | (unsigned int)tid;
      stat[1] = rk0 - nxt;
    }
    __syncthreads();
  }
  const unsigned int T = stat[0];
  const unsigned int rkeep = stat[1];
  const float rowmax = __uint_as_float(stat[2]);
  const float s = 127.0f / fmaxf(rowmax, 1e-5f);
  unsigned int cnt = 0;
#pragma unroll
  for (int j = 0; j < 8; ++j) cnt += (bits[tid * 8 + j] == T) ? 1u : 0u;
  scn[tid] = cnt;
  __syncthreads();
  for (int off = 1; off < 256; off <<= 1) {
    unsigned int v = (tid >= off) ? scn[tid - off] : 0u;
    __syncthreads();
    scn[tid] += v;
    __syncthreads();
  }
  unsigned int eqr = scn[tid] - cnt;
#pragma unroll
  for (int j = 0; j < 8; ++j) {
    int i = tid * 8 + j;
    unsigned int u = bits[i];
    bool keep = u > T;
    if (u == T) { keep = (eqr < rkeep); eqr++; }
    float q = 0.0f;
    if (keep) {
      q = rintf(xr[i] * s);
      q = fminf(fmaxf(q, -128.0f), 127.0f);
    }
    oq[(size_t)row * 2048 + i] = (signed char)q;
  }
  if (tid == 0) so[row] = s;
}

// ---------------------------------------------------------------------------
extern "C" void kernel_launch(void* const* d_in, const int* in_sizes, int n_in,
                              void* d_out, int out_size, void* d_ws,
                              size_t ws_size, hipStream_t stream) {
  const float* x = (const float*)d_in[0];
  const float* wq = (const float*)d_in[1];
  const float* wk = (const float*)d_in[2];
  const float* wv = (const float*)d_in[3];
  const float* wo = (const float*)d_in[4];
  float* out = (float*)d_out;

  char* ws = (char*)d_ws;
  size_t off = 0;
  auto alloc = [&](size_t bytes) -> void* {
    void* p = ws + off;
    off += (bytes + 255) & ~(size_t)255;
    return p;
  };
  signed char* wt = (signed char*)alloc(4ull * 2048 * 2048);  // 16.8MB
  signed char* xq = (signed char*)alloc(4096ull * 2048);      // 8.4MB
  float* qb = (float*)alloc(4096ull * 2048 * 4);              // 33.5MB
  signed char* oq = (signed char*)alloc(4096ull * 2048);      // 8.4MB
  _Float16* kfh = (_Float16*)alloc(32ull * 64 * 8 * 512 * 2);  // 16.8MB
  _Float16* kfl = (_Float16*)alloc(32ull * 64 * 8 * 512 * 2);  // 16.8MB
  _Float16* vfh = (_Float16*)alloc(32ull * 64 * 8 * 512 * 2);  // 16.8MB
  _Float16* vfl = (_Float16*)alloc(32ull * 64 * 8 * 512 * 2);  // 16.8MB
  float* ct = (float*)alloc(2048ull * 64 * 4);
  float* st = (float*)alloc(2048ull * 64 * 4);
  float* sx = (float*)alloc(4096 * 4);
  float* so = (float*)alloc(4096 * 4);
  float* wsc = (float*)alloc(4 * 4);
  double* prt = (double*)alloc(4096 * 8);

  k_costab<<<512, 256, 0, stream>>>(ct, st);
  k_wsum<<<4096, 256, 0, stream>>>(wq, wk, wv, wo, prt);
  k_wscale<<<4, 256, 0, stream>>>(prt, wsc);
  k_wquant<<<dim3(1024, 4), 256, 0, stream>>>(wq, wk, wv, wo, wsc, wt);
  k_xquant<<<4096, 256, 0, stream>>>(x, xq, sx);

  k_gemm3<<<dim3(48, 32), 256, 0, stream>>>(xq, wt, qb, kfh, kfl, vfh, vfl,
                                            sx, wsc, ct, st);
  k_attn<<<512, 256, 0, stream>>>(qb, kfh, kfl, vfh, vfl);  // O -> qb
  k_topk<<<4096, 256, 0, stream>>>(qb, oq, so);
  k_gemm<<<dim3(16, 32), 256, 0, stream>>>(oq, wt + 3ull * 4194304, out, so,
                                           wsc + 3);
}

// Round 13
// 422.554 us; speedup vs baseline: 1.0496x; 1.0496x over previous
//
#include <hip/hip_runtime.h>
#include <stdint.h>
#include <math.h>

// ---------------------------------------------------------------------------
// BitAttention: B=2, T=2048, D=2048, H=16, HD=128
//   q/k/v = int4-quant(x) @ ternary(w)^T   (exact int math via i8 MFMA)
//   RoPE + K/V f16-split fused into GEMM epilogue; MFMA flash attention
//   (f16 hi/lo 3-term split, GLDS staging, T15 softmax/QK overlap pipeline,
//   defer-max, permlane32_swap repack, setprio, conflict-free V swizzle)
//   out = int8-quant(topk_0.55(attn)) @ ternary(wo)^T (exact int via i8 MFMA)
// ---------------------------------------------------------------------------

typedef __attribute__((ext_vector_type(8))) short short8;
typedef __attribute__((ext_vector_type(4))) int i32x4;
typedef __attribute__((ext_vector_type(8))) _Float16 f16x8;
typedef __attribute__((ext_vector_type(16))) float f32x16;

#define GLDS16(g, l)                                                        \
  __builtin_amdgcn_global_load_lds(                                         \
      (const __attribute__((address_space(1))) void*)(g),                   \
      (__attribute__((address_space(3))) void*)(l), 16, 0, 0)

__device__ __forceinline__ unsigned short f2bf(float v) {
  return (unsigned short)(__float_as_uint(v) >> 16);
}

// ---------------- cos/sin tables (T x 64), faithful f32 path ---------------
__global__ __launch_bounds__(256) void k_costab(float* __restrict__ ct,
                                                float* __restrict__ st) {
  int idx = blockIdx.x * 256 + threadIdx.x;  // 2048*64
  int t = idx >> 6, i = idx & 63;
  float f = (float)(2 * i) / 128.0f;
  float inv = 1.0f / powf(10000.0f, f);
  float fr = (float)t * inv;
  ct[idx] = cosf(fr);
  st[idx] = sinf(fr);
}

// ---------------- weight scale: mean(|w|), deterministic f64 tree ----------
__global__ __launch_bounds__(256) void k_wsum(const float* __restrict__ w0,
                                              const float* __restrict__ w1,
                                              const float* __restrict__ w2,
                                              const float* __restrict__ w3,
                                              double* __restrict__ part) {
  int bx = blockIdx.x;  // 0..4095 ; 1024 blocks per matrix
  int mat = bx >> 10;
  const float* w = (mat == 0) ? w0 : (mat == 1) ? w1 : (mat == 2) ? w2 : w3;
  int base = (bx & 1023) * 4096;
  double s = 0.0;
#pragma unroll
  for (int i = 0; i < 16; ++i)
    s += (double)fabsf(w[base + threadIdx.x + i * 256]);
  __shared__ double red[256];
  red[threadIdx.x] = s;
  __syncthreads();
  for (int off = 128; off; off >>= 1) {
    if (threadIdx.x < off) red[threadIdx.x] += red[threadIdx.x + off];
    __syncthreads();
  }
  if (threadIdx.x == 0) part[bx] = red[0];
}

__global__ __launch_bounds__(256) void k_wscale(const double* __restrict__ part,
                                                float* __restrict__ wsc) {
  int m = blockIdx.x, tid = threadIdx.x;
  const double* p = part + m * 1024;
  double s = p[tid] + p[tid + 256] + p[tid + 512] + p[tid + 768];
  __shared__ double red[256];
  red[tid] = s;
  __syncthreads();
  for (int off = 128; off; off >>= 1) {
    if (tid < off) red[tid] += red[tid + off];
    __syncthreads();
  }
  if (tid == 0) wsc[m] = (float)(red[0] / 4194304.0);
}

// ---------------- ternary quantize weights -> int8 {-1,0,1} ----------------
__global__ __launch_bounds__(256) void k_wquant(const float* __restrict__ w0,
                                                const float* __restrict__ w1,
                                                const float* __restrict__ w2,
                                                const float* __restrict__ w3,
                                                const float* __restrict__ wsc,
                                                signed char* __restrict__ wt) {
  int mat = blockIdx.y;
  const float* w = (mat == 0) ? w0 : (mat == 1) ? w1 : (mat == 2) ? w2 : w3;
  float se = wsc[mat] + 1e-5f;
  size_t base = (size_t)blockIdx.x * 4096;
  signed char* o = wt + (size_t)mat * 4194304 + base;
  const float* wp = w + base;
#pragma unroll 4
  for (int i = 0; i < 16; ++i) {
    int idx = threadIdx.x + i * 256;
    float v = rintf(wp[idx] / se);
    v = fminf(fmaxf(v, -1.0f), 1.0f);
    o[idx] = (signed char)v;
  }
}

// ---------------- int4 row-quantize x -> int8 + 1/s scale ------------------
__global__ __launch_bounds__(256) void k_xquant(const float* __restrict__ x,
                                                signed char* __restrict__ xq,
                                                float* __restrict__ sx) {
  int row = blockIdx.x, tid = threadIdx.x;
  const float* xr = x + (size_t)row * 2048;
  float v[8];
  float mx = 0.0f;
#pragma unroll
  for (int i = 0; i < 8; ++i) {
    v[i] = xr[tid + i * 256];
    mx = fmaxf(mx, fabsf(v[i]));
  }
  __shared__ float red[256];
  red[tid] = mx;
  __syncthreads();
  for (int off = 128; off; off >>= 1) {
    if (tid < off) red[tid] = fmaxf(red[tid], red[tid + off]);
    __syncthreads();
  }
  float s = 7.0f / fmaxf(red[0], 1e-5f);
#pragma unroll
  for (int i = 0; i < 8; ++i) {
    float q = rintf(v[i] * s);
    q = fminf(fmaxf(q, -8.0f), 7.0f);
    xq[(size_t)row * 2048 + tid + i * 256] = (signed char)q;
  }
  if (tid == 0) sx[row] = s;
}

// ---------------- fused QKV i8 GEMM + RoPE / V-transpose epilogue ----------
__global__ __launch_bounds__(256) void k_gemm3(const signed char* __restrict__ A,
                                               const signed char* __restrict__ wtall,
                                               float* __restrict__ qo,
                                               _Float16* __restrict__ khp,
                                               _Float16* __restrict__ klp,
                                               _Float16* __restrict__ vth,
                                               _Float16* __restrict__ vtl,
                                               const float* __restrict__ srow,
                                               const float* __restrict__ wsc,
                                               const float* __restrict__ ct,
                                               const float* __restrict__ st) {
  __shared__ alignas(16) signed char As[128 * 64];
  __shared__ alignas(16) signed char Bs[128 * 64];
  __shared__ float fac[128];
  const int tid = threadIdx.x, wave = tid >> 6, lane = tid & 63;
  const int bxi = blockIdx.x;
  const int mat = bxi >> 4;
  const signed char* Bw = wtall + (size_t)mat * 4194304;
  const int brow = blockIdx.y * 128, bcol = (bxi & 15) * 128;
  if (tid < 128) fac[tid] = wsc[mat] / srow[brow + tid];
  const int wr = wave >> 1, wc = wave & 1;
  i32x4 acc[4][4];
#pragma unroll
  for (int m = 0; m < 4; ++m)
#pragma unroll
    for (int n = 0; n < 4; ++n) acc[m][n] = (i32x4){0, 0, 0, 0};
  const int srl = tid >> 2;                            // staged row 0..63
  const int ssw = ((tid & 3) ^ ((srl >> 1) & 3)) * 16; // swizzled k-offset
  const signed char* Ag = A + (size_t)(brow + srl) * 2048 + ssw;
  const signed char* Bg = Bw + (size_t)(bcol + srl) * 2048 + ssw;
  char* AsB = (char*)As + wave * 1024;
  char* BsB = (char*)Bs + wave * 1024;
  const int fr = lane & 15, kb = lane >> 4;
  const int rsl = (kb ^ ((fr >> 1) & 3)) * 16;  // swizzled read slot
  for (int k0 = 0; k0 < 2048; k0 += 64) {
    __syncthreads();
    GLDS16(Ag + k0, AsB);
    GLDS16(Ag + k0 + (size_t)64 * 2048, AsB + 4096);
    GLDS16(Bg + k0, BsB);
    GLDS16(Bg + k0 + (size_t)64 * 2048, BsB + 4096);
    __syncthreads();
    i32x4 af[4], bf[4];
#pragma unroll
    for (int m = 0; m < 4; ++m)
      af[m] = *(const i32x4*)&As[(wr * 64 + m * 16 + fr) * 64 + rsl];
#pragma unroll
    for (int n = 0; n < 4; ++n)
      bf[n] = *(const i32x4*)
           &Bs[(wc * 32 + (n & 1) * 16 + (n >> 1) * 64 + fr) * 64 + rsl];
#pragma unroll
    for (int m = 0; m < 4; ++m)
#pragma unroll
      for (int n = 0; n < 4; ++n)
        acc[m][n] = __builtin_amdgcn_mfma_i32_16x16x64_i8(af[m], bf[n],
                                                          acc[m][n], 0, 0, 0);
  }
  const int fq = lane >> 4;
  const int hh = bcol >> 7;  // head index
  const int bb0 = brow >> 11, tbase = brow & 2047;
  if (mat == 2) {
    // ---- V: transpose via LDS quarters -> f16 hi/lo planes ----
    _Float16* Ah = (_Float16*)As;  // [32 d][128 t] hi plane (8KB)
    _Float16* Al = (_Float16*)Bs;  // lo plane
    const int bh = bb0 * 16 + hh;
#pragma unroll
    for (int q = 0; q < 4; ++q) {
      __syncthreads();  // LDS free
      if (wc == (q & 1)) {
#pragma unroll
        for (int m = 0; m < 4; ++m)
#pragma unroll
          for (int nn = 0; nn < 2; ++nn) {
            int n = (q >> 1) * 2 + nn;
            int dl = nn * 16 + fr;
#pragma unroll
            for (int r = 0; r < 4; ++r) {
              int tl = wr * 64 + m * 16 + fq * 4 + r;
              float val = (float)acc[m][n][r] * fac[tl];
              _Float16 hv = (_Float16)val;
              Ah[dl * 128 + tl] = hv;
              Al[dl * 128 + tl] = (_Float16)(val - (float)hv);
            }
          }
      }
      __syncthreads();
      {
        int d = tid >> 3, tseg = (tid & 7) * 16;
        size_t ob = ((size_t)bh * 128 + q * 32 + d) * 2048 + tbase + tseg;
        *(f16x8*)(vth + ob) = *(const f16x8*)&Ah[d * 128 + tseg];
        *(f16x8*)(vth + ob + 8) = *(const f16x8*)&Ah[d * 128 + tseg + 8];
        *(f16x8*)(vtl + ob) = *(const f16x8*)&Al[d * 128 + tseg];
        *(f16x8*)(vtl + ob + 8) = *(const f16x8*)&Al[d * 128 + tseg + 8];
      }
    }
  } else {
#pragma unroll
    for (int m = 0; m < 4; ++m)
#pragma unroll
      for (int n = 0; n < 2; ++n) {
        int d1 = wc * 32 + n * 16 + fr;  // [0,64)
#pragma unroll
        for (int r = 0; r < 4; ++r) {
          int row = wr * 64 + m * 16 + fq * 4 + r;
          int rg = brow + row;
          int t = rg & 2047;
          float c = ct[t * 64 + d1], sn = st[t * 64 + d1];
          float x1 = (float)acc[m][n][r] * fac[row];
          float x2 = (float)acc[m][n + 2][r] * fac[row];
          float y1 = x1 * c - x2 * sn;
          float y2 = x2 * c + x1 * sn;
          if (mat == 0) {
            qo[(size_t)rg * 2048 + bcol + d1] = y1;
            qo[(size_t)rg * 2048 + bcol + d1 + 64] = y2;
          } else {
            size_t ob = ((size_t)(bb0 * 16 + hh) * 2048 + t) * 128 + d1;
            _Float16 h1 = (_Float16)y1, h2 = (_Float16)y2;
            khp[ob] = h1;
            khp[ob + 64] = h2;
            klp[ob] = (_Float16)(y1 - (float)h1);
            klp[ob + 64] = (_Float16)(y2 - (float)h2);
          }
        }
      }
  }
}

// ---------------- single i8 GEMM (output projection) -----------------------
__global__ __launch_bounds__(256) void k_gemm(const signed char* __restrict__ A,
                                              const signed char* __restrict__ Bw,
                                              float* __restrict__ C,
                                              const float* __restrict__ srow,
                                              const float* __restrict__ wsp) {
  __shared__ alignas(16) signed char As[128 * 64];
  __shared__ alignas(16) signed char Bs[128 * 64];
  __shared__ float fac[128];
  const int tid = threadIdx.x, wave = tid >> 6, lane = tid & 63;
  const int brow = blockIdx.y * 128, bcol = blockIdx.x * 128;
  if (tid < 128) fac[tid] = wsp[0] / srow[brow + tid];
  const int wr = wave >> 1, wc = wave & 1;
  i32x4 acc[4][4];
#pragma unroll
  for (int m = 0; m < 4; ++m)
#pragma unroll
    for (int n = 0; n < 4; ++n) acc[m][n] = (i32x4){0, 0, 0, 0};
  const int srl = tid >> 2;
  const int ssw = ((tid & 3) ^ ((srl >> 1) & 3)) * 16;
  const signed char* Ag = A + (size_t)(brow + srl) * 2048 + ssw;
  const signed char* Bg = Bw + (size_t)(bcol + srl) * 2048 + ssw;
  char* AsB = (char*)As + wave * 1024;
  char* BsB = (char*)Bs + wave * 1024;
  const int fr = lane & 15, kb = lane >> 4;
  const int rsl = (kb ^ ((fr >> 1) & 3)) * 16;
  for (int k0 = 0; k0 < 2048; k0 += 64) {
    __syncthreads();
    GLDS16(Ag + k0, AsB);
    GLDS16(Ag + k0 + (size_t)64 * 2048, AsB + 4096);
    GLDS16(Bg + k0, BsB);
    GLDS16(Bg + k0 + (size_t)64 * 2048, BsB + 4096);
    __syncthreads();
    i32x4 af[4], bf[4];
#pragma unroll
    for (int m = 0; m < 4; ++m)
      af[m] = *(const i32x4*)&As[(wr * 64 + m * 16 + fr) * 64 + rsl];
#pragma unroll
    for (int n = 0; n < 4; ++n)
      bf[n] = *(const i32x4*)&Bs[(wc * 64 + n * 16 + fr) * 64 + rsl];
#pragma unroll
    for (int m = 0; m < 4; ++m)
#pragma unroll
      for (int n = 0; n < 4; ++n)
        acc[m][n] = __builtin_amdgcn_mfma_i32_16x16x64_i8(af[m], bf[n],
                                                          acc[m][n], 0, 0, 0);
  }
  const int fq = lane >> 4;
#pragma unroll
  for (int m = 0; m < 4; ++m)
#pragma unroll
    for (int n = 0; n < 4; ++n)
#pragma unroll
      for (int r = 0; r < 4; ++r) {
        int row = wr * 64 + m * 16 + fq * 4 + r;
        C[(size_t)(brow + row) * 2048 + bcol + wc * 64 + n * 16 + fr] =
            (float)acc[m][n][r] * fac[row];
      }
}

// ---------------- MFMA flash attention (T15 pipelined) ---------------------
// 4 waves, 128 q rows/block. K-tile 32, 32x32x16 f16 MFMAs, hi/lo 3-term
// split. GLDS staging (source-swizzled), K/V double-buffered, 1 barrier/tile.
// T15: iteration t runs QK(t) MFMA concurrently with softmax(t-1) VALU, then
// PV(t-1). exp2-domain softmax, defer-max, permlane32_swap repack, setprio.
// V swizzle uses (row>>1)&3 (64B rows: row-pairs cover all 8 bank groups).
__global__ __launch_bounds__(256, 2) void k_attn(float* __restrict__ qb,
                                                 const _Float16* __restrict__ kh,
                                                 const _Float16* __restrict__ kl,
                                                 const _Float16* __restrict__ vth,
                                                 const _Float16* __restrict__ vtl) {
  __shared__ alignas(16) char KS[2][2][32 * 256];  // 32 KiB
  __shared__ alignas(16) char VS[2][2][128 * 64];  // 32 KiB
  const int tid = threadIdx.x;
  const int wave = tid >> 6, lane = tid & 63;
  const int rl = lane & 31, hi = lane >> 5, hi8 = hi * 8;
  const int bid = blockIdx.x;
  const int xcd = bid & 7, li = bid >> 3;            // XCD-aware: 4 bh per XCD
  const int bh = xcd * 4 + (li >> 4), qt = li & 15;  // bijective over 512
  const int b = bh >> 4, h = bh & 15;
  const size_t rowbase = (size_t)b * 2048;
  const int hcol = h * 128;
  const float F = 0.08838834764831845f * 1.44269504088896f;  // SCALE*log2e
  const float THR = 11.5415603f;                             // 8*log2e

  // ---- Q fragments (hi/lo f16, SCALE*log2e prefolded) ----
  f16x8 qh[8], ql[8];
  {
    const float* qsrc =
        qb + (rowbase + qt * 128 + wave * 32 + rl) * 2048 + hcol + hi8;
#pragma unroll
    for (int ds = 0; ds < 8; ++ds) {
      float4 a = *(const float4*)(qsrc + ds * 16);
      float4 c = *(const float4*)(qsrc + ds * 16 + 4);
      float v[8] = {a.x, a.y, a.z, a.w, c.x, c.y, c.z, c.w};
      f16x8 hh, ll;
#pragma unroll
      for (int i = 0; i < 8; ++i) {
        float sv = v[i] * F;
        _Float16 hv = (_Float16)sv;
        hh[i] = hv;
        ll[i] = (_Float16)(sv - (float)hv);
      }
      qh[ds] = hh;
      ql[ds] = ll;
    }
  }

  // ---- GLDS staging geometry (source-swizzled, linear LDS dest) ----
  const int krl = lane >> 4, ksl = lane & 15;  // K: 4 rows/inst, 16 slots
  const int vrl = lane >> 2, vsl = lane & 3;   // V: 16 rows/inst, 4 slots
  size_t kofs[2], vofs[2];
#pragma unroll
  for (int i = 0; i < 2; ++i) {
    int krow = wave * 8 + i * 4 + krl;
    kofs[i] = (size_t)krow * 128 + ((ksl ^ (krow & 7)) << 3);
    int vrow = wave * 32 + i * 16 + vrl;
    vofs[i] = (size_t)vrow * 2048 + ((vsl ^ ((vrow >> 1) & 3)) << 3);
  }
  const _Float16* gkh = kh + (size_t)bh * 262144;
  const _Float16* gkl = kl + (size_t)bh * 262144;
  const _Float16* gvh = vth + (size_t)bh * 262144;
  const _Float16* gvl = vtl + (size_t)bh * 262144;

  f32x16 Oa[4];
#pragma unroll
  for (int df = 0; df < 4; ++df)
#pragma unroll
    for (int i = 0; i < 16; ++i) Oa[df][i] = 0.0f;
  float m = -INFINITY, lsum = 0.0f;
  f32x16 sPrev;

  // prologue: stage K[0] into Kbuf 0
#pragma unroll
  for (int i = 0; i < 2; ++i) {
    GLDS16(gkh + kofs[i], KS[0][0] + wave * 2048 + i * 1024);
    GLDS16(gkl + kofs[i], KS[0][1] + wave * 2048 + i * 1024);
  }

  for (int kt = 0; kt < 64; ++kt) {
    const int bf = kt & 1;
    __syncthreads();  // drains vmcnt: K[kt] and (kt>0) V[kt-1] staged
    // ---- async stage K[kt+1] -> Kbuf[bf^1], V[kt] -> Vbuf[bf] ----
    if (kt < 63) {
      const _Float16* pkh = gkh + (size_t)(kt + 1) * 4096;
      const _Float16* pkl = gkl + (size_t)(kt + 1) * 4096;
      char* kd0 = KS[bf ^ 1][0] + wave * 2048;
      char* kd1 = KS[bf ^ 1][1] + wave * 2048;
#pragma unroll
      for (int i = 0; i < 2; ++i) {
        GLDS16(pkh + kofs[i], kd0 + i * 1024);
        GLDS16(pkl + kofs[i], kd1 + i * 1024);
      }
    }
    {
      const _Float16* pvh = gvh + (size_t)kt * 32;
      const _Float16* pvl = gvl + (size_t)kt * 32;
      char* vd0 = VS[bf][0] + wave * 2048;
      char* vd1 = VS[bf][1] + wave * 2048;
#pragma unroll
      for (int i = 0; i < 2; ++i) {
        GLDS16(pvh + vofs[i], vd0 + i * 1024);
        GLDS16(pvl + vofs[i], vd1 + i * 1024);
      }
    }
    // ---- QK(kt): 3 independent chains from Kbuf[bf] ----
    f32x16 sA = {}, sB = {}, sC = {};
    __builtin_amdgcn_s_setprio(1);
#pragma unroll
    for (int ds = 0; ds < 8; ++ds) {
      const int ra = rl * 256 + (((2 * ds + hi) ^ (rl & 7)) << 4);
      f16x8 ah = *(const f16x8*)(KS[bf][0] + ra);
      f16x8 al = *(const f16x8*)(KS[bf][1] + ra);
      sA = __builtin_amdgcn_mfma_f32_32x32x16_f16(ah, qh[ds], sA, 0, 0, 0);
      sB = __builtin_amdgcn_mfma_f32_32x32x16_f16(ah, ql[ds], sB, 0, 0, 0);
      sC = __builtin_amdgcn_mfma_f32_32x32x16_f16(al, qh[ds], sC, 0, 0, 0);
    }
    __builtin_amdgcn_s_setprio(0);
    // ---- softmax(kt-1) on sPrev (independent of QK(kt) -> overlaps) ----
    if (kt > 0) {
      const int pbf = (kt - 1) & 1;
      float pm = fmaxf(
          fmaxf(fmaxf(fmaxf(sPrev[0], sPrev[1]), fmaxf(sPrev[2], sPrev[3])),
                fmaxf(fmaxf(sPrev[4], sPrev[5]), fmaxf(sPrev[6], sPrev[7]))),
          fmaxf(fmaxf(fmaxf(sPrev[8], sPrev[9]), fmaxf(sPrev[10], sPrev[11])),
                fmaxf(fmaxf(sPrev[12], sPrev[13]),
                      fmaxf(sPrev[14], sPrev[15]))));
      pm = fmaxf(pm, __shfl_xor(pm, 32));
      float alpha = 1.0f;
      if (__any(pm > m + THR)) {  // rare after tile 0
        float mn = fmaxf(m, pm);
        alpha = exp2f(m - mn);  // m=-inf -> 0
        m = mn;
#pragma unroll
        for (int reg = 0; reg < 16; ++reg) {
          int qr = (reg & 3) + 8 * (reg >> 2) + 4 * hi;
          float av = __shfl(alpha, qr);
          Oa[0][reg] *= av;
          Oa[1][reg] *= av;
          Oa[2][reg] *= av;
          Oa[3][reg] *= av;
        }
      }
      unsigned int pkhh[4][2], pkll[4][2];
      float ls = 0.0f;
#pragma unroll
      for (int t4 = 0; t4 < 4; ++t4)
#pragma unroll
        for (int c2 = 0; c2 < 2; ++c2) {
          float pa = exp2f(sPrev[4 * t4 + 2 * c2] - m);
          float pb = exp2f(sPrev[4 * t4 + 2 * c2 + 1] - m);
          ls += pa + pb;
          auto hp = __builtin_amdgcn_cvt_pkrtz(pa, pb);
          float la = pa - (float)hp[0], lb = pb - (float)hp[1];
          auto lp = __builtin_amdgcn_cvt_pkrtz(la, lb);
          pkhh[t4][c2] = __builtin_bit_cast(unsigned int, hp);
          pkll[t4][c2] = __builtin_bit_cast(unsigned int, lp);
        }
      ls += __shfl_xor(ls, 32);
      lsum = lsum * alpha + ls;
      f16x8 paH[2], paL[2];
#pragma unroll
      for (int hf = 0; hf < 2; ++hf) {
        {
          unsigned int a0 = pkhh[2 * hf][0], b0 = pkhh[2 * hf + 1][0];
          unsigned int a1 = pkhh[2 * hf][1], b1 = pkhh[2 * hf + 1][1];
          asm("v_permlane32_swap_b32 %0, %1" : "+v"(a0), "+v"(b0));
          asm("v_permlane32_swap_b32 %0, %1" : "+v"(a1), "+v"(b1));
          uint4 u;
          u.x = a0; u.y = a1; u.z = b0; u.w = b1;
          paH[hf] = __builtin_bit_cast(f16x8, u);
        }
        {
          unsigned int a0 = pkll[2 * hf][0], b0 = pkll[2 * hf + 1][0];
          unsigned int a1 = pkll[2 * hf][1], b1 = pkll[2 * hf + 1][1];
          asm("v_permlane32_swap_b32 %0, %1" : "+v"(a0), "+v"(b0));
          asm("v_permlane32_swap_b32 %0, %1" : "+v"(a1), "+v"(b1));
          uint4 u;
          u.x = a0; u.y = a1; u.z = b0; u.w = b1;
          paL[hf] = __builtin_bit_cast(f16x8, u);
        }
      }
      // ---- PV(kt-1) from Vbuf[pbf] ----
      __builtin_amdgcn_s_setprio(1);
#pragma unroll
      for (int df = 0; df < 4; ++df) {
#pragma unroll
        for (int hf = 0; hf < 2; ++hf) {
          const int va =
              (df * 32 + rl) * 64 + (((2 * hf + hi) ^ ((rl >> 1) & 3)) << 4);
          f16x8 vh = *(const f16x8*)(VS[pbf][0] + va);
          f16x8 vl = *(const f16x8*)(VS[pbf][1] + va);
          Oa[df] = __builtin_amdgcn_mfma_f32_32x32x16_f16(paH[hf], vh, Oa[df], 0, 0, 0);
          Oa[df] = __builtin_amdgcn_mfma_f32_32x32x16_f16(paH[hf], vl, Oa[df], 0, 0, 0);
          Oa[df] = __builtin_amdgcn_mfma_f32_32x32x16_f16(paL[hf], vh, Oa[df], 0, 0, 0);
        }
      }
      __builtin_amdgcn_s_setprio(0);
    }
    // ---- merge QK(kt) chains -> sPrev ----
#pragma unroll
    for (int i = 0; i < 16; ++i) sPrev[i] = (sA[i] + sB[i]) + sC[i];
  }
  // ---- epilogue: softmax(63) + PV(63) ----
  __syncthreads();  // V[63] staged
  {
    float pm = fmaxf(
        fmaxf(fmaxf(fmaxf(sPrev[0], sPrev[1]), fmaxf(sPrev[2], sPrev[3])),
              fmaxf(fmaxf(sPrev[4], sPrev[5]), fmaxf(sPrev[6], sPrev[7]))),
        fmaxf(fmaxf(fmaxf(sPrev[8], sPrev[9]), fmaxf(sPrev[10], sPrev[11])),
              fmaxf(fmaxf(sPrev[12], sPrev[13]),
                    fmaxf(sPrev[14], sPrev[15]))));
    pm = fmaxf(pm, __shfl_xor(pm, 32));
    float alpha = 1.0f;
    if (__any(pm > m + THR)) {
      float mn = fmaxf(m, pm);
      alpha = exp2f(m - mn);
      m = mn;
#pragma unroll
      for (int reg = 0; reg < 16; ++reg) {
        int qr = (reg & 3) + 8 * (reg >> 2) + 4 * hi;
        float av = __shfl(alpha, qr);
        Oa[0][reg] *= av;
        Oa[1][reg] *= av;
        Oa[2][reg] *= av;
        Oa[3][reg] *= av;
      }
    }
    unsigned int pkhh[4][2], pkll[4][2];
    float ls = 0.0f;
#pragma unroll
    for (int t4 = 0; t4 < 4; ++t4)
#pragma unroll
      for (int c2 = 0; c2 < 2; ++c2) {
        float pa = exp2f(sPrev[4 * t4 + 2 * c2] - m);
        float pb = exp2f(sPrev[4 * t4 + 2 * c2 + 1] - m);
        ls += pa + pb;
        auto hp = __builtin_amdgcn_cvt_pkrtz(pa, pb);
        float la = pa - (float)hp[0], lb = pb - (float)hp[1];
        auto lp = __builtin_amdgcn_cvt_pkrtz(la, lb);
        pkhh[t4][c2] = __builtin_bit_cast(unsigned int, hp);
        pkll[t4][c2] = __builtin_bit_cast(unsigned int, lp);
      }
    ls += __shfl_xor(ls, 32);
    lsum = lsum * alpha + ls;
    f16x8 paH[2], paL[2];
#pragma unroll
    for (int hf = 0; hf < 2; ++hf) {
      {
        unsigned int a0 = pkhh[2 * hf][0], b0 = pkhh[2 * hf + 1][0];
        unsigned int a1 = pkhh[2 * hf][1], b1 = pkhh[2 * hf + 1][1];
        asm("v_permlane32_swap_b32 %0, %1" : "+v"(a0), "+v"(b0));
        asm("v_permlane32_swap_b32 %0, %1" : "+v"(a1), "+v"(b1));
        uint4 u;
        u.x = a0; u.y = a1; u.z = b0; u.w = b1;
        paH[hf] = __builtin_bit_cast(f16x8, u);
      }
      {
        unsigned int a0 = pkll[2 * hf][0], b0 = pkll[2 * hf + 1][0];
        unsigned int a1 = pkll[2 * hf][1], b1 = pkll[2 * hf + 1][1];
        asm("v_permlane32_swap_b32 %0, %1" : "+v"(a0), "+v"(b0));
        asm("v_permlane32_swap_b32 %0, %1" : "+v"(a1), "+v"(b1));
        uint4 u;
        u.x = a0; u.y = a1; u.z = b0; u.w = b1;
        paL[hf] = __builtin_bit_cast(f16x8, u);
      }
    }
#pragma unroll
    for (int df = 0; df < 4; ++df) {
#pragma unroll
      for (int hf = 0; hf < 2; ++hf) {
        const int va =
            (df * 32 + rl) * 64 + (((2 * hf + hi) ^ ((rl >> 1) & 3)) << 4);
        f16x8 vh = *(const f16x8*)(VS[1][0] + va);
        f16x8 vl = *(const f16x8*)(VS[1][1] + va);
        Oa[df] = __builtin_amdgcn_mfma_f32_32x32x16_f16(paH[hf], vh, Oa[df], 0, 0, 0);
        Oa[df] = __builtin_amdgcn_mfma_f32_32x32x16_f16(paH[hf], vl, Oa[df], 0, 0, 0);
        Oa[df] = __builtin_amdgcn_mfma_f32_32x32x16_f16(paL[hf], vh, Oa[df], 0, 0, 0);
      }
    }
  }
  // ---- normalize + store in-place into our own q rows ----
  float linv = 1.0f / lsum;
  float* obase = qb + (rowbase + qt * 128 + wave * 32) * 2048 + hcol;
#pragma unroll
  for (int reg = 0; reg < 16; ++reg) {
    int qr = (reg & 3) + 8 * (reg >> 2) + 4 * hi;
    float lv = __shfl(linv, qr);
    float* orow = obase + (size_t)qr * 2048;
    orow[0 * 32 + rl] = Oa[0][reg] * lv;
    orow[1 * 32 + rl] = Oa[1][reg] * lv;
    orow[2 * 32 + rl] = Oa[2][reg] * lv;
    orow[3 * 32 + rl] = Oa[3][reg] * lv;
  }
}

// ---------------- topk(0.55)+int8 quantize per row ------------------------
// Exact tie handling; wave-level shfl scans (4 barriers/radix-pass vs 19).
__global__ __launch_bounds__(256) void k_topk(const float* __restrict__ ain,
                                              signed char* __restrict__ oq,
                                              float* __restrict__ so) {
  const int row = blockIdx.x, tid = threadIdx.x;
  const int wave = tid >> 6, lane = tid & 63;
  const float* xr = ain + (size_t)row * 2048;
  __shared__ unsigned int bits[2048];
  __shared__ unsigned int hist[256];
  __shared__ unsigned int wtot[4];
  __shared__ unsigned int stat[3];  // prefix, rk, maxbits
  unsigned int mx = 0;
#pragma unroll
  for (int j = 0; j < 8; ++j) {
    int i = tid * 8 + j;
    unsigned int u = __float_as_uint(xr[i]) & 0x7fffffffu;
    bits[i] = u;
    mx = max(mx, u);
  }
#pragma unroll
  for (int off = 32; off; off >>= 1)
    mx = max(mx, (unsigned int)__shfl_xor((int)mx, off));
  if (lane == 0) wtot[wave] = mx;
  __syncthreads();
  if (tid == 0) {
    stat[0] = 0u;
    stat[1] = 1126u;
    stat[2] = max(max(wtot[0], wtot[1]), max(wtot[2], wtot[3]));
  }
  // 4-pass radix select (exact 32-bit threshold)
  for (int p = 0; p < 4; ++p) {
    const int shift = 24 - 8 * p;
    hist[tid] = 0u;
    __syncthreads();  // hist zeroed; stat from prev pass visible
    unsigned int pref = stat[0];
    unsigned int rk0 = stat[1];
#pragma unroll
    for (int j = 0; j < 8; ++j) {
      unsigned int u = bits[tid * 8 + j];
      bool match = (p == 0) || ((u >> (shift + 8)) == pref);
      if (match) atomicAdd(&hist[(u >> shift) & 255u], 1u);
    }
    __syncthreads();  // hist complete
    // suffix scan: full[tid] = sum_{b >= tid} hist[b]
    unsigned int v = hist[tid];
#pragma unroll
    for (int off = 1; off < 64; off <<= 1) {
      unsigned int t = (unsigned int)__shfl_down((int)v, off);
      if (lane + off < 64) v += t;
    }
    if (lane == 0) wtot[wave] = v;  // wave's 64-bin total
    __syncthreads();
    unsigned int add = 0;
#pragma unroll
    for (int w = 0; w < 4; ++w)
      if (w > wave) add += wtot[w];
    unsigned int full = v + add;
    unsigned int nxt = (unsigned int)__shfl_down((int)full, 1);
    if (lane == 63) nxt = add;  // next tid's full (0 for tid 255)
    if (full >= rk0 && nxt < rk0) {
      stat[0] = (pref << 8) | (unsigned int)tid;
      stat[1] = rk0 - nxt;
    }
    __syncthreads();  // stat updated
  }
  const unsigned int T = stat[0];
  const unsigned int rkeep = stat[1];
  const float rowmax = __uint_as_float(stat[2]);
  const float s = 127.0f / fmaxf(rowmax, 1e-5f);
  // rank-among-equals (index order): exclusive prefix of per-thread counts
  unsigned int cnt = 0;
#pragma unroll
  for (int j = 0; j < 8; ++j) cnt += (bits[tid * 8 + j] == T) ? 1u : 0u;
  unsigned int c = cnt;
#pragma unroll
  for (int off = 1; off < 64; off <<= 1) {
    unsigned int t = (unsigned int)__shfl_up((int)c, off);
    if (lane >= off) c += t;
  }
  if (lane == 63) wtot[wave] = c;  // wave total (inclusive of whole wave)
  __syncthreads();
  unsigned int pre = 0;
#pragma unroll
  for (int w = 0; w < 4; ++w)
    if (w < wave) pre += wtot[w];
  unsigned int eqr = pre + c - cnt;
#pragma unroll
  for (int j = 0; j < 8; ++j) {
    int i = tid * 8 + j;
    unsigned int u = bits[i];
    bool keep = u > T;
    if (u == T) { keep = (eqr < rkeep); eqr++; }
    float q = 0.0f;
    if (keep) {
      q = rintf(xr[i] * s);
      q = fminf(fmaxf(q, -128.0f), 127.0f);
    }
    oq[(size_t)row * 2048 + i] = (signed char)q;
  }
  if (tid == 0) so[row] = s;
}

// ---------------------------------------------------------------------------
extern "C" void kernel_launch(void* const* d_in, const int* in_sizes, int n_in,
                              void* d_out, int out_size, void* d_ws,
                              size_t ws_size, hipStream_t stream) {
  const float* x = (const float*)d_in[0];
  const float* wq = (const float*)d_in[1];
  const float* wk = (const float*)d_in[2];
  const float* wv = (const float*)d_in[3];
  const float* wo = (const float*)d_in[4];
  float* out = (float*)d_out;

  char* ws = (char*)d_ws;
  size_t off = 0;
  auto alloc = [&](size_t bytes) -> void* {
    void* p = ws + off;
    off += (bytes + 255) & ~(size_t)255;
    return p;
  };
  signed char* wt = (signed char*)alloc(4ull * 2048 * 2048);  // 16.8MB
  signed char* xq = (signed char*)alloc(4096ull * 2048);      // 8.4MB
  float* qb = (float*)alloc(4096ull * 2048 * 4);              // 33.5MB
  signed char* oq = (signed char*)alloc(4096ull * 2048);      // 8.4MB
  _Float16* kh = (_Float16*)alloc(32ull * 2048 * 128 * 2);   // 16.8MB
  _Float16* kl = (_Float16*)alloc(32ull * 2048 * 128 * 2);   // 16.8MB
  _Float16* vth = (_Float16*)alloc(32ull * 128 * 2048 * 2);  // 16.8MB
  _Float16* vtl = (_Float16*)alloc(32ull * 128 * 2048 * 2);  // 16.8MB
  float* ct = (float*)alloc(2048ull * 64 * 4);
  float* st = (float*)alloc(2048ull * 64 * 4);
  float* sx = (float*)alloc(4096 * 4);
  float* so = (float*)alloc(4096 * 4);
  float* wsc = (float*)alloc(4 * 4);
  double* prt = (double*)alloc(4096 * 8);

  k_costab<<<512, 256, 0, stream>>>(ct, st);
  k_wsum<<<4096, 256, 0, stream>>>(wq, wk, wv, wo, prt);
  k_wscale<<<4, 256, 0, stream>>>(prt, wsc);
  k_wquant<<<dim3(1024, 4), 256, 0, stream>>>(wq, wk, wv, wo, wsc, wt);
  k_xquant<<<4096, 256, 0, stream>>>(x, xq, sx);

  k_gemm3<<<dim3(48, 32), 256, 0, stream>>>(xq, wt, qb, kh, kl, vth, vtl, sx,
                                            wsc, ct, st);
  k_attn<<<512, 256, 0, stream>>>(qb, kh, kl, vth, vtl);  // O -> qb in-place
  k_topk<<<4096, 256, 0, stream>>>(qb, oq, so);
  k_gemm<<<dim3(16, 32), 256, 0, stream>>>(oq, wt + 3ull * 4194304, out, so,
                                           wsc + 3);
}

// Round 14
// 409.716 us; speedup vs baseline: 1.0825x; 1.0313x over previous
//
#include <hip/hip_runtime.h>
#include <stdint.h>
#include <math.h>

// ---------------------------------------------------------------------------
// BitAttention: B=2, T=2048, D=2048, H=16, HD=128
//   q/k/v = int4-quant(x) @ ternary(w)^T   (exact int math via i8 MFMA)
//   RoPE + K/V f16-split fused into GEMM epilogue; MFMA flash attention
//   (f16 hi/lo 3-term split, GLDS staging, T15 softmax/QK overlap pipeline,
//   defer-max, permlane32_swap repack, setprio, conflict-free V swizzle)
//   out = int8-quant(topk_0.55(attn)) @ ternary(wo)^T (exact int via i8 MFMA)
// ---------------------------------------------------------------------------

typedef __attribute__((ext_vector_type(8))) short short8;
typedef __attribute__((ext_vector_type(4))) int i32x4;
typedef __attribute__((ext_vector_type(8))) _Float16 f16x8;
typedef __attribute__((ext_vector_type(16))) float f32x16;

#define GLDS16(g, l)                                                        \
  __builtin_amdgcn_global_load_lds(                                         \
      (const __attribute__((address_space(1))) void*)(g),                   \
      (__attribute__((address_space(3))) void*)(l), 16, 0, 0)

// ---------------- cos/sin tables (T x 64), faithful f32 path ---------------
__global__ __launch_bounds__(256) void k_costab(float* __restrict__ ct,
                                                float* __restrict__ st) {
  int idx = blockIdx.x * 256 + threadIdx.x;  // 2048*64
  int t = idx >> 6, i = idx & 63;
  float f = (float)(2 * i) / 128.0f;
  float inv = 1.0f / powf(10000.0f, f);
  float fr = (float)t * inv;
  ct[idx] = cosf(fr);
  st[idx] = sinf(fr);
}

// ---------------- weight scale: mean(|w|), deterministic f64 tree ----------
__global__ __launch_bounds__(256) void k_wsum(const float* __restrict__ w0,
                                              const float* __restrict__ w1,
                                              const float* __restrict__ w2,
                                              const float* __restrict__ w3,
                                              double* __restrict__ part) {
  int bx = blockIdx.x;  // 0..4095 ; 1024 blocks per matrix
  int mat = bx >> 10;
  const float* w = (mat == 0) ? w0 : (mat == 1) ? w1 : (mat == 2) ? w2 : w3;
  const float4* w4 = (const float4*)(w + (size_t)(bx & 1023) * 4096);
  double s = 0.0;
#pragma unroll
  for (int i = 0; i < 4; ++i) {
    float4 v = w4[threadIdx.x + i * 256];
    s += (double)fabsf(v.x) + (double)fabsf(v.y) + (double)fabsf(v.z) +
         (double)fabsf(v.w);
  }
  __shared__ double red[256];
  red[threadIdx.x] = s;
  __syncthreads();
  for (int off = 128; off; off >>= 1) {
    if (threadIdx.x < off) red[threadIdx.x] += red[threadIdx.x + off];
    __syncthreads();
  }
  if (threadIdx.x == 0) part[bx] = red[0];
}

__global__ __launch_bounds__(256) void k_wscale(const double* __restrict__ part,
                                                float* __restrict__ wsc) {
  int m = blockIdx.x, tid = threadIdx.x;
  const double* p = part + m * 1024;
  double s = p[tid] + p[tid + 256] + p[tid + 512] + p[tid + 768];
  __shared__ double red[256];
  red[tid] = s;
  __syncthreads();
  for (int off = 128; off; off >>= 1) {
    if (tid < off) red[tid] += red[tid + off];
    __syncthreads();
  }
  if (tid == 0) wsc[m] = (float)(red[0] / 4194304.0);
}

// ---------------- ternary quantize weights -> int8 {-1,0,1} ----------------
__global__ __launch_bounds__(256) void k_wquant(const float* __restrict__ w0,
                                                const float* __restrict__ w1,
                                                const float* __restrict__ w2,
                                                const float* __restrict__ w3,
                                                const float* __restrict__ wsc,
                                                signed char* __restrict__ wt) {
  int mat = blockIdx.y;
  const float* w = (mat == 0) ? w0 : (mat == 1) ? w1 : (mat == 2) ? w2 : w3;
  float se = wsc[mat] + 1e-5f;
  size_t base = (size_t)blockIdx.x * 4096;
  const float4* wp4 = (const float4*)(w + base);
  char4* o4 = (char4*)(wt + (size_t)mat * 4194304 + base);
#pragma unroll
  for (int i = 0; i < 4; ++i) {
    float4 v = wp4[threadIdx.x + i * 256];
    char4 c;
    c.x = (signed char)fminf(fmaxf(rintf(v.x / se), -1.0f), 1.0f);
    c.y = (signed char)fminf(fmaxf(rintf(v.y / se), -1.0f), 1.0f);
    c.z = (signed char)fminf(fmaxf(rintf(v.z / se), -1.0f), 1.0f);
    c.w = (signed char)fminf(fmaxf(rintf(v.w / se), -1.0f), 1.0f);
    o4[threadIdx.x + i * 256] = c;
  }
}

// ---------------- int4 row-quantize x -> int8 + 1/s scale ------------------
__global__ __launch_bounds__(256) void k_xquant(const float* __restrict__ x,
                                                signed char* __restrict__ xq,
                                                float* __restrict__ sx) {
  int row = blockIdx.x, tid = threadIdx.x;
  const float* xr = x + (size_t)row * 2048;
  float4 va = *(const float4*)(xr + tid * 8);
  float4 vb = *(const float4*)(xr + tid * 8 + 4);
  float v[8] = {va.x, va.y, va.z, va.w, vb.x, vb.y, vb.z, vb.w};
  float mx = 0.0f;
#pragma unroll
  for (int i = 0; i < 8; ++i) mx = fmaxf(mx, fabsf(v[i]));
  __shared__ float red[256];
  red[tid] = mx;
  __syncthreads();
  for (int off = 128; off; off >>= 1) {
    if (tid < off) red[tid] = fmaxf(red[tid], red[tid + off]);
    __syncthreads();
  }
  float s = 7.0f / fmaxf(red[0], 1e-5f);
  unsigned int pk[2] = {0u, 0u};
#pragma unroll
  for (int i = 0; i < 8; ++i) {
    float q = fminf(fmaxf(rintf(v[i] * s), -8.0f), 7.0f);
    pk[i >> 2] |= ((unsigned int)(unsigned char)(signed char)q) << ((i & 3) * 8);
  }
  *(uint2*)(xq + (size_t)row * 2048 + tid * 8) = make_uint2(pk[0], pk[1]);
  if (tid == 0) sx[row] = s;
}

// ---------------- fused QKV i8 GEMM + RoPE / V-transpose epilogue ----------
__global__ __launch_bounds__(256) void k_gemm3(const signed char* __restrict__ A,
                                               const signed char* __restrict__ wtall,
                                               float* __restrict__ qo,
                                               _Float16* __restrict__ khp,
                                               _Float16* __restrict__ klp,
                                               _Float16* __restrict__ vth,
                                               _Float16* __restrict__ vtl,
                                               const float* __restrict__ srow,
                                               const float* __restrict__ wsc,
                                               const float* __restrict__ ct,
                                               const float* __restrict__ st) {
  __shared__ alignas(16) signed char As[128 * 64];
  __shared__ alignas(16) signed char Bs[128 * 64];
  __shared__ float fac[128];
  const int tid = threadIdx.x, wave = tid >> 6, lane = tid & 63;
  const int bxi = blockIdx.x;
  const int mat = bxi >> 4;
  const signed char* Bw = wtall + (size_t)mat * 4194304;
  const int brow = blockIdx.y * 128, bcol = (bxi & 15) * 128;
  if (tid < 128) fac[tid] = wsc[mat] / srow[brow + tid];
  const int wr = wave >> 1, wc = wave & 1;
  i32x4 acc[4][4];
#pragma unroll
  for (int m = 0; m < 4; ++m)
#pragma unroll
    for (int n = 0; n < 4; ++n) acc[m][n] = (i32x4){0, 0, 0, 0};
  const int srl = tid >> 2;                            // staged row 0..63
  const int ssw = ((tid & 3) ^ ((srl >> 1) & 3)) * 16; // swizzled k-offset
  const signed char* Ag = A + (size_t)(brow + srl) * 2048 + ssw;
  const signed char* Bg = Bw + (size_t)(bcol + srl) * 2048 + ssw;
  char* AsB = (char*)As + wave * 1024;
  char* BsB = (char*)Bs + wave * 1024;
  const int fr = lane & 15, kb = lane >> 4;
  const int rsl = (kb ^ ((fr >> 1) & 3)) * 16;  // swizzled read slot
  for (int k0 = 0; k0 < 2048; k0 += 64) {
    __syncthreads();
    GLDS16(Ag + k0, AsB);
    GLDS16(Ag + k0 + (size_t)64 * 2048, AsB + 4096);
    GLDS16(Bg + k0, BsB);
    GLDS16(Bg + k0 + (size_t)64 * 2048, BsB + 4096);
    __syncthreads();
    i32x4 af[4], bf[4];
#pragma unroll
    for (int m = 0; m < 4; ++m)
      af[m] = *(const i32x4*)&As[(wr * 64 + m * 16 + fr) * 64 + rsl];
#pragma unroll
    for (int n = 0; n < 4; ++n)
      bf[n] = *(const i32x4*)
           &Bs[(wc * 32 + (n & 1) * 16 + (n >> 1) * 64 + fr) * 64 + rsl];
#pragma unroll
    for (int m = 0; m < 4; ++m)
#pragma unroll
      for (int n = 0; n < 4; ++n)
        acc[m][n] = __builtin_amdgcn_mfma_i32_16x16x64_i8(af[m], bf[n],
                                                          acc[m][n], 0, 0, 0);
  }
  const int fq = lane >> 4;
  const int hh = bcol >> 7;  // head index
  const int bb0 = brow >> 11, tbase = brow & 2047;
  if (mat == 2) {
    // ---- V: transpose via LDS quarters -> f16 hi/lo planes ----
    _Float16* Ah = (_Float16*)As;  // [32 d][128 t] hi plane (8KB)
    _Float16* Al = (_Float16*)Bs;  // lo plane
    const int bh = bb0 * 16 + hh;
#pragma unroll
    for (int q = 0; q < 4; ++q) {
      __syncthreads();  // LDS free
      if (wc == (q & 1)) {
#pragma unroll
        for (int m = 0; m < 4; ++m)
#pragma unroll
          for (int nn = 0; nn < 2; ++nn) {
            int n = (q >> 1) * 2 + nn;
            int dl = nn * 16 + fr;
#pragma unroll
            for (int r = 0; r < 4; ++r) {
              int tl = wr * 64 + m * 16 + fq * 4 + r;
              float val = (float)acc[m][n][r] * fac[tl];
              _Float16 hv = (_Float16)val;
              Ah[dl * 128 + tl] = hv;
              Al[dl * 128 + tl] = (_Float16)(val - (float)hv);
            }
          }
      }
      __syncthreads();
      {
        int d = tid >> 3, tseg = (tid & 7) * 16;
        size_t ob = ((size_t)bh * 128 + q * 32 + d) * 2048 + tbase + tseg;
        *(f16x8*)(vth + ob) = *(const f16x8*)&Ah[d * 128 + tseg];
        *(f16x8*)(vth + ob + 8) = *(const f16x8*)&Ah[d * 128 + tseg + 8];
        *(f16x8*)(vtl + ob) = *(const f16x8*)&Al[d * 128 + tseg];
        *(f16x8*)(vtl + ob + 8) = *(const f16x8*)&Al[d * 128 + tseg + 8];
      }
    }
  } else {
#pragma unroll
    for (int m = 0; m < 4; ++m)
#pragma unroll
      for (int n = 0; n < 2; ++n) {
        int d1 = wc * 32 + n * 16 + fr;  // [0,64)
#pragma unroll
        for (int r = 0; r < 4; ++r) {
          int row = wr * 64 + m * 16 + fq * 4 + r;
          int rg = brow + row;
          int t = rg & 2047;
          float c = ct[t * 64 + d1], sn = st[t * 64 + d1];
          float x1 = (float)acc[m][n][r] * fac[row];
          float x2 = (float)acc[m][n + 2][r] * fac[row];
          float y1 = x1 * c - x2 * sn;
          float y2 = x2 * c + x1 * sn;
          if (mat == 0) {
            qo[(size_t)rg * 2048 + bcol + d1] = y1;
            qo[(size_t)rg * 2048 + bcol + d1 + 64] = y2;
          } else {
            size_t ob = ((size_t)(bb0 * 16 + hh) * 2048 + t) * 128 + d1;
            _Float16 h1 = (_Float16)y1, h2 = (_Float16)y2;
            khp[ob] = h1;
            khp[ob + 64] = h2;
            klp[ob] = (_Float16)(y1 - (float)h1);
            klp[ob + 64] = (_Float16)(y2 - (float)h2);
          }
        }
      }
  }
}

// ---------------- single i8 GEMM (output projection) -----------------------
__global__ __launch_bounds__(256) void k_gemm(const signed char* __restrict__ A,
                                              const signed char* __restrict__ Bw,
                                              float* __restrict__ C,
                                              const float* __restrict__ srow,
                                              const float* __restrict__ wsp) {
  __shared__ alignas(16) signed char As[128 * 64];
  __shared__ alignas(16) signed char Bs[128 * 64];
  __shared__ float fac[128];
  const int tid = threadIdx.x, wave = tid >> 6, lane = tid & 63;
  const int brow = blockIdx.y * 128, bcol = blockIdx.x * 128;
  if (tid < 128) fac[tid] = wsp[0] / srow[brow + tid];
  const int wr = wave >> 1, wc = wave & 1;
  i32x4 acc[4][4];
#pragma unroll
  for (int m = 0; m < 4; ++m)
#pragma unroll
    for (int n = 0; n < 4; ++n) acc[m][n] = (i32x4){0, 0, 0, 0};
  const int srl = tid >> 2;
  const int ssw = ((tid & 3) ^ ((srl >> 1) & 3)) * 16;
  const signed char* Ag = A + (size_t)(brow + srl) * 2048 + ssw;
  const signed char* Bg = Bw + (size_t)(bcol + srl) * 2048 + ssw;
  char* AsB = (char*)As + wave * 1024;
  char* BsB = (char*)Bs + wave * 1024;
  const int fr = lane & 15, kb = lane >> 4;
  const int rsl = (kb ^ ((fr >> 1) & 3)) * 16;
  for (int k0 = 0; k0 < 2048; k0 += 64) {
    __syncthreads();
    GLDS16(Ag + k0, AsB);
    GLDS16(Ag + k0 + (size_t)64 * 2048, AsB + 4096);
    GLDS16(Bg + k0, BsB);
    GLDS16(Bg + k0 + (size_t)64 * 2048, BsB + 4096);
    __syncthreads();
    i32x4 af[4], bf[4];
#pragma unroll
    for (int m = 0; m < 4; ++m)
      af[m] = *(const i32x4*)&As[(wr * 64 + m * 16 + fr) * 64 + rsl];
#pragma unroll
    for (int n = 0; n < 4; ++n)
      bf[n] = *(const i32x4*)&Bs[(wc * 64 + n * 16 + fr) * 64 + rsl];
#pragma unroll
    for (int m = 0; m < 4; ++m)
#pragma unroll
      for (int n = 0; n < 4; ++n)
        acc[m][n] = __builtin_amdgcn_mfma_i32_16x16x64_i8(af[m], bf[n],
                                                          acc[m][n], 0, 0, 0);
  }
  const int fq = lane >> 4;
#pragma unroll
  for (int m = 0; m < 4; ++m)
#pragma unroll
    for (int n = 0; n < 4; ++n)
#pragma unroll
      for (int r = 0; r < 4; ++r) {
        int row = wr * 64 + m * 16 + fq * 4 + r;
        C[(size_t)(brow + row) * 2048 + bcol + wc * 64 + n * 16 + fr] =
            (float)acc[m][n][r] * fac[row];
      }
}

// ---------------- MFMA flash attention (T15 pipelined) ---------------------
// 4 waves, 128 q rows/block. K-tile 32, 32x32x16 f16 MFMAs, hi/lo 3-term
// split. GLDS staging (source-swizzled), K/V double-buffered, 1 barrier/tile.
// T15: iteration t runs QK(t) MFMA concurrently with softmax(t-1) VALU, then
// PV(t-1). exp2-domain softmax, defer-max, permlane32_swap repack, setprio.
// V swizzle uses (row>>1)&3 (64B rows: row-pairs cover all 8 bank groups).
__global__ __launch_bounds__(256, 2) void k_attn(float* __restrict__ qb,
                                                 const _Float16* __restrict__ kh,
                                                 const _Float16* __restrict__ kl,
                                                 const _Float16* __restrict__ vth,
                                                 const _Float16* __restrict__ vtl) {
  __shared__ alignas(16) char KS[2][2][32 * 256];  // 32 KiB
  __shared__ alignas(16) char VS[2][2][128 * 64];  // 32 KiB
  const int tid = threadIdx.x;
  const int wave = tid >> 6, lane = tid & 63;
  const int rl = lane & 31, hi = lane >> 5, hi8 = hi * 8;
  const int bid = blockIdx.x;
  const int xcd = bid & 7, li = bid >> 3;            // XCD-aware: 4 bh per XCD
  const int bh = xcd * 4 + (li >> 4), qt = li & 15;  // bijective over 512
  const int b = bh >> 4, h = bh & 15;
  const size_t rowbase = (size_t)b * 2048;
  const int hcol = h * 128;
  const float F = 0.08838834764831845f * 1.44269504088896f;  // SCALE*log2e
  const float THR = 11.5415603f;                             // 8*log2e

  // ---- Q fragments (hi/lo f16, SCALE*log2e prefolded) ----
  f16x8 qh[8], ql[8];
  {
    const float* qsrc =
        qb + (rowbase + qt * 128 + wave * 32 + rl) * 2048 + hcol + hi8;
#pragma unroll
    for (int ds = 0; ds < 8; ++ds) {
      float4 a = *(const float4*)(qsrc + ds * 16);
      float4 c = *(const float4*)(qsrc + ds * 16 + 4);
      float v[8] = {a.x, a.y, a.z, a.w, c.x, c.y, c.z, c.w};
      f16x8 hh, ll;
#pragma unroll
      for (int i = 0; i < 8; ++i) {
        float sv = v[i] * F;
        _Float16 hv = (_Float16)sv;
        hh[i] = hv;
        ll[i] = (_Float16)(sv - (float)hv);
      }
      qh[ds] = hh;
      ql[ds] = ll;
    }
  }

  // ---- GLDS staging geometry (source-swizzled, linear LDS dest) ----
  const int krl = lane >> 4, ksl = lane & 15;  // K: 4 rows/inst, 16 slots
  const int vrl = lane >> 2, vsl = lane & 3;   // V: 16 rows/inst, 4 slots
  size_t kofs[2], vofs[2];
#pragma unroll
  for (int i = 0; i < 2; ++i) {
    int krow = wave * 8 + i * 4 + krl;
    kofs[i] = (size_t)krow * 128 + ((ksl ^ (krow & 7)) << 3);
    int vrow = wave * 32 + i * 16 + vrl;
    vofs[i] = (size_t)vrow * 2048 + ((vsl ^ ((vrow >> 1) & 3)) << 3);
  }
  const _Float16* gkh = kh + (size_t)bh * 262144;
  const _Float16* gkl = kl + (size_t)bh * 262144;
  const _Float16* gvh = vth + (size_t)bh * 262144;
  const _Float16* gvl = vtl + (size_t)bh * 262144;

  f32x16 Oa[4];
#pragma unroll
  for (int df = 0; df < 4; ++df)
#pragma unroll
    for (int i = 0; i < 16; ++i) Oa[df][i] = 0.0f;
  float m = -INFINITY, lsum = 0.0f;
  f32x16 sPrev;

  // prologue: stage K[0] into Kbuf 0
#pragma unroll
  for (int i = 0; i < 2; ++i) {
    GLDS16(gkh + kofs[i], KS[0][0] + wave * 2048 + i * 1024);
    GLDS16(gkl + kofs[i], KS[0][1] + wave * 2048 + i * 1024);
  }

  for (int kt = 0; kt < 64; ++kt) {
    const int bf = kt & 1;
    __syncthreads();  // drains vmcnt: K[kt] and (kt>0) V[kt-1] staged
    // ---- async stage K[kt+1] -> Kbuf[bf^1], V[kt] -> Vbuf[bf] ----
    if (kt < 63) {
      const _Float16* pkh = gkh + (size_t)(kt + 1) * 4096;
      const _Float16* pkl = gkl + (size_t)(kt + 1) * 4096;
      char* kd0 = KS[bf ^ 1][0] + wave * 2048;
      char* kd1 = KS[bf ^ 1][1] + wave * 2048;
#pragma unroll
      for (int i = 0; i < 2; ++i) {
        GLDS16(pkh + kofs[i], kd0 + i * 1024);
        GLDS16(pkl + kofs[i], kd1 + i * 1024);
      }
    }
    {
      const _Float16* pvh = gvh + (size_t)kt * 32;
      const _Float16* pvl = gvl + (size_t)kt * 32;
      char* vd0 = VS[bf][0] + wave * 2048;
      char* vd1 = VS[bf][1] + wave * 2048;
#pragma unroll
      for (int i = 0; i < 2; ++i) {
        GLDS16(pvh + vofs[i], vd0 + i * 1024);
        GLDS16(pvl + vofs[i], vd1 + i * 1024);
      }
    }
    // ---- QK(kt): 3 independent chains from Kbuf[bf] ----
    f32x16 sA = {}, sB = {}, sC = {};
    __builtin_amdgcn_s_setprio(1);
#pragma unroll
    for (int ds = 0; ds < 8; ++ds) {
      const int ra = rl * 256 + (((2 * ds + hi) ^ (rl & 7)) << 4);
      f16x8 ah = *(const f16x8*)(KS[bf][0] + ra);
      f16x8 al = *(const f16x8*)(KS[bf][1] + ra);
      sA = __builtin_amdgcn_mfma_f32_32x32x16_f16(ah, qh[ds], sA, 0, 0, 0);
      sB = __builtin_amdgcn_mfma_f32_32x32x16_f16(ah, ql[ds], sB, 0, 0, 0);
      sC = __builtin_amdgcn_mfma_f32_32x32x16_f16(al, qh[ds], sC, 0, 0, 0);
    }
    __builtin_amdgcn_s_setprio(0);
    // ---- softmax(kt-1) on sPrev (independent of QK(kt) -> overlaps) ----
    if (kt > 0) {
      const int pbf = (kt - 1) & 1;
      float pm = fmaxf(
          fmaxf(fmaxf(fmaxf(sPrev[0], sPrev[1]), fmaxf(sPrev[2], sPrev[3])),
                fmaxf(fmaxf(sPrev[4], sPrev[5]), fmaxf(sPrev[6], sPrev[7]))),
          fmaxf(fmaxf(fmaxf(sPrev[8], sPrev[9]), fmaxf(sPrev[10], sPrev[11])),
                fmaxf(fmaxf(sPrev[12], sPrev[13]),
                      fmaxf(sPrev[14], sPrev[15]))));
      pm = fmaxf(pm, __shfl_xor(pm, 32));
      float alpha = 1.0f;
      if (__any(pm > m + THR)) {  // rare after tile 0
        float mn = fmaxf(m, pm);
        alpha = exp2f(m - mn);  // m=-inf -> 0
        m = mn;
#pragma unroll
        for (int reg = 0; reg < 16; ++reg) {
          int qr = (reg & 3) + 8 * (reg >> 2) + 4 * hi;
          float av = __shfl(alpha, qr);
          Oa[0][reg] *= av;
          Oa[1][reg] *= av;
          Oa[2][reg] *= av;
          Oa[3][reg] *= av;
        }
      }
      unsigned int pkhh[4][2], pkll[4][2];
      float ls = 0.0f;
#pragma unroll
      for (int t4 = 0; t4 < 4; ++t4)
#pragma unroll
        for (int c2 = 0; c2 < 2; ++c2) {
          float pa = exp2f(sPrev[4 * t4 + 2 * c2] - m);
          float pb = exp2f(sPrev[4 * t4 + 2 * c2 + 1] - m);
          ls += pa + pb;
          auto hp = __builtin_amdgcn_cvt_pkrtz(pa, pb);
          float la = pa - (float)hp[0], lb = pb - (float)hp[1];
          auto lp = __builtin_amdgcn_cvt_pkrtz(la, lb);
          pkhh[t4][c2] = __builtin_bit_cast(unsigned int, hp);
          pkll[t4][c2] = __builtin_bit_cast(unsigned int, lp);
        }
      ls += __shfl_xor(ls, 32);
      lsum = lsum * alpha + ls;
      f16x8 paH[2], paL[2];
#pragma unroll
      for (int hf = 0; hf < 2; ++hf) {
        {
          unsigned int a0 = pkhh[2 * hf][0], b0 = pkhh[2 * hf + 1][0];
          unsigned int a1 = pkhh[2 * hf][1], b1 = pkhh[2 * hf + 1][1];
          asm("v_permlane32_swap_b32 %0, %1" : "+v"(a0), "+v"(b0));
          asm("v_permlane32_swap_b32 %0, %1" : "+v"(a1), "+v"(b1));
          uint4 u;
          u.x = a0; u.y = a1; u.z = b0; u.w = b1;
          paH[hf] = __builtin_bit_cast(f16x8, u);
        }
        {
          unsigned int a0 = pkll[2 * hf][0], b0 = pkll[2 * hf + 1][0];
          unsigned int a1 = pkll[2 * hf][1], b1 = pkll[2 * hf + 1][1];
          asm("v_permlane32_swap_b32 %0, %1" : "+v"(a0), "+v"(b0));
          asm("v_permlane32_swap_b32 %0, %1" : "+v"(a1), "+v"(b1));
          uint4 u;
          u.x = a0; u.y = a1; u.z = b0; u.w = b1;
          paL[hf] = __builtin_bit_cast(f16x8, u);
        }
      }
      // ---- PV(kt-1) from Vbuf[pbf] ----
      __builtin_amdgcn_s_setprio(1);
#pragma unroll
      for (int df = 0; df < 4; ++df) {
#pragma unroll
        for (int hf = 0; hf < 2; ++hf) {
          const int va =
              (df * 32 + rl) * 64 + (((2 * hf + hi) ^ ((rl >> 1) & 3)) << 4);
          f16x8 vh = *(const f16x8*)(VS[pbf][0] + va);
          f16x8 vl = *(const f16x8*)(VS[pbf][1] + va);
          Oa[df] = __builtin_amdgcn_mfma_f32_32x32x16_f16(paH[hf], vh, Oa[df], 0, 0, 0);
          Oa[df] = __builtin_amdgcn_mfma_f32_32x32x16_f16(paH[hf], vl, Oa[df], 0, 0, 0);
          Oa[df] = __builtin_amdgcn_mfma_f32_32x32x16_f16(paL[hf], vh, Oa[df], 0, 0, 0);
        }
      }
      __builtin_amdgcn_s_setprio(0);
    }
    // ---- merge QK(kt) chains -> sPrev ----
#pragma unroll
    for (int i = 0; i < 16; ++i) sPrev[i] = (sA[i] + sB[i]) + sC[i];
  }
  // ---- epilogue: softmax(63) + PV(63) ----
  __syncthreads();  // V[63] staged
  {
    float pm = fmaxf(
        fmaxf(fmaxf(fmaxf(sPrev[0], sPrev[1]), fmaxf(sPrev[2], sPrev[3])),
              fmaxf(fmaxf(sPrev[4], sPrev[5]), fmaxf(sPrev[6], sPrev[7]))),
        fmaxf(fmaxf(fmaxf(sPrev[8], sPrev[9]), fmaxf(sPrev[10], sPrev[11])),
              fmaxf(fmaxf(sPrev[12], sPrev[13]),
                    fmaxf(sPrev[14], sPrev[15]))));
    pm = fmaxf(pm, __shfl_xor(pm, 32));
    float alpha = 1.0f;
    if (__any(pm > m + THR)) {
      float mn = fmaxf(m, pm);
      alpha = exp2f(m - mn);
      m = mn;
#pragma unroll
      for (int reg = 0; reg < 16; ++reg) {
        int qr = (reg & 3) + 8 * (reg >> 2) + 4 * hi;
        float av = __shfl(alpha, qr);
        Oa[0][reg] *= av;
        Oa[1][reg] *= av;
        Oa[2][reg] *= av;
        Oa[3][reg] *= av;
      }
    }
    unsigned int pkhh[4][2], pkll[4][2];
    float ls = 0.0f;
#pragma unroll
    for (int t4 = 0; t4 < 4; ++t4)
#pragma unroll
      for (int c2 = 0; c2 < 2; ++c2) {
        float pa = exp2f(sPrev[4 * t4 + 2 * c2] - m);
        float pb = exp2f(sPrev[4 * t4 + 2 * c2 + 1] - m);
        ls += pa + pb;
        auto hp = __builtin_amdgcn_cvt_pkrtz(pa, pb);
        float la = pa - (float)hp[0], lb = pb - (float)hp[1];
        auto lp = __builtin_amdgcn_cvt_pkrtz(la, lb);
        pkhh[t4][c2] = __builtin_bit_cast(unsigned int, hp);
        pkll[t4][c2] = __builtin_bit_cast(unsigned int, lp);
      }
    ls += __shfl_xor(ls, 32);
    lsum = lsum * alpha + ls;
    f16x8 paH[2], paL[2];
#pragma unroll
    for (int hf = 0; hf < 2; ++hf) {
      {
        unsigned int a0 = pkhh[2 * hf][0], b0 = pkhh[2 * hf + 1][0];
        unsigned int a1 = pkhh[2 * hf][1], b1 = pkhh[2 * hf + 1][1];
        asm("v_permlane32_swap_b32 %0, %1" : "+v"(a0), "+v"(b0));
        asm("v_permlane32_swap_b32 %0, %1" : "+v"(a1), "+v"(b1));
        uint4 u;
        u.x = a0; u.y = a1; u.z = b0; u.w = b1;
        paH[hf] = __builtin_bit_cast(f16x8, u);
      }
      {
        unsigned int a0 = pkll[2 * hf][0], b0 = pkll[2 * hf + 1][0];
        unsigned int a1 = pkll[2 * hf][1], b1 = pkll[2 * hf + 1][1];
        asm("v_permlane32_swap_b32 %0, %1" : "+v"(a0), "+v"(b0));
        asm("v_permlane32_swap_b32 %0, %1" : "+v"(a1), "+v"(b1));
        uint4 u;
        u.x = a0; u.y = a1; u.z = b0; u.w = b1;
        paL[hf] = __builtin_bit_cast(f16x8, u);
      }
    }
#pragma unroll
    for (int df = 0; df < 4; ++df) {
#pragma unroll
      for (int hf = 0; hf < 2; ++hf) {
        const int va =
            (df * 32 + rl) * 64 + (((2 * hf + hi) ^ ((rl >> 1) & 3)) << 4);
        f16x8 vh = *(const f16x8*)(VS[1][0] + va);
        f16x8 vl = *(const f16x8*)(VS[1][1] + va);
        Oa[df] = __builtin_amdgcn_mfma_f32_32x32x16_f16(paH[hf], vh, Oa[df], 0, 0, 0);
        Oa[df] = __builtin_amdgcn_mfma_f32_32x32x16_f16(paH[hf], vl, Oa[df], 0, 0, 0);
        Oa[df] = __builtin_amdgcn_mfma_f32_32x32x16_f16(paL[hf], vh, Oa[df], 0, 0, 0);
      }
    }
  }
  // ---- normalize + store in-place into our own q rows ----
  float linv = 1.0f / lsum;
  float* obase = qb + (rowbase + qt * 128 + wave * 32) * 2048 + hcol;
#pragma unroll
  for (int reg = 0; reg < 16; ++reg) {
    int qr = (reg & 3) + 8 * (reg >> 2) + 4 * hi;
    float lv = __shfl(linv, qr);
    float* orow = obase + (size_t)qr * 2048;
    orow[0 * 32 + rl] = Oa[0][reg] * lv;
    orow[1 * 32 + rl] = Oa[1][reg] * lv;
    orow[2 * 32 + rl] = Oa[2][reg] * lv;
    orow[3 * 32 + rl] = Oa[3][reg] * lv;
  }
}

// ---------------- topk(0.55)+int8 quantize per row ------------------------
// Exact tie handling; element data held in REGISTERS (all accesses are
// thread-private); wave-level shfl scans.
__global__ __launch_bounds__(256) void k_topk(const float* __restrict__ ain,
                                              signed char* __restrict__ oq,
                                              float* __restrict__ so) {
  const int row = blockIdx.x, tid = threadIdx.x;
  const int wave = tid >> 6, lane = tid & 63;
  const float* xr = ain + (size_t)row * 2048;
  __shared__ unsigned int hist[256];
  __shared__ unsigned int wtot[4];
  __shared__ unsigned int stat[3];  // prefix, rk, maxbits
  float4 va = *(const float4*)(xr + tid * 8);
  float4 vb = *(const float4*)(xr + tid * 8 + 4);
  float v[8] = {va.x, va.y, va.z, va.w, vb.x, vb.y, vb.z, vb.w};
  unsigned int u[8];
  unsigned int mx = 0;
#pragma unroll
  for (int j = 0; j < 8; ++j) {
    u[j] = __float_as_uint(v[j]) & 0x7fffffffu;
    mx = max(mx, u[j]);
  }
#pragma unroll
  for (int off = 32; off; off >>= 1)
    mx = max(mx, (unsigned int)__shfl_xor((int)mx, off));
  if (lane == 0) wtot[wave] = mx;
  __syncthreads();
  if (tid == 0) {
    stat[0] = 0u;
    stat[1] = 1126u;
    stat[2] = max(max(wtot[0], wtot[1]), max(wtot[2], wtot[3]));
  }
  // 4-pass radix select (exact 32-bit threshold)
  for (int p = 0; p < 4; ++p) {
    const int shift = 24 - 8 * p;
    hist[tid] = 0u;
    __syncthreads();  // hist zeroed; stat from prev pass visible
    unsigned int pref = stat[0];
    unsigned int rk0 = stat[1];
#pragma unroll
    for (int j = 0; j < 8; ++j) {
      bool match = (p == 0) || ((u[j] >> (shift + 8)) == pref);
      if (match) atomicAdd(&hist[(u[j] >> shift) & 255u], 1u);
    }
    __syncthreads();  // hist complete
    // suffix scan: full[tid] = sum_{b >= tid} hist[b]
    unsigned int s = hist[tid];
#pragma unroll
    for (int off = 1; off < 64; off <<= 1) {
      unsigned int t = (unsigned int)__shfl_down((int)s, off);
      if (lane + off < 64) s += t;
    }
    if (lane == 0) wtot[wave] = s;  // wave's 64-bin total
    __syncthreads();
    unsigned int add = 0;
#pragma unroll
    for (int w = 0; w < 4; ++w)
      if (w > wave) add += wtot[w];
    unsigned int full = s + add;
    unsigned int nxt = (unsigned int)__shfl_down((int)full, 1);
    if (lane == 63) nxt = add;  // next tid's full (0 for tid 255)
    if (full >= rk0 && nxt < rk0) {
      stat[0] = (pref << 8) | (unsigned int)tid;
      stat[1] = rk0 - nxt;
    }
    __syncthreads();  // stat updated
  }
  const unsigned int T = stat[0];
  const unsigned int rkeep = stat[1];
  const float rowmax = __uint_as_float(stat[2]);
  const float s = 127.0f / fmaxf(rowmax, 1e-5f);
  // rank-among-equals (index order): exclusive prefix of per-thread counts
  unsigned int cnt = 0;
#pragma unroll
  for (int j = 0; j < 8; ++j) cnt += (u[j] == T) ? 1u : 0u;
  unsigned int c = cnt;
#pragma unroll
  for (int off = 1; off < 64; off <<= 1) {
    unsigned int t = (unsigned int)__shfl_up((int)c, off);
    if (lane >= off) c += t;
  }
  if (lane == 63) wtot[wave] = c;  // wave total (inclusive of whole wave)
  __syncthreads();
  unsigned int pre = 0;
#pragma unroll
  for (int w = 0; w < 4; ++w)
    if (w < wave) pre += wtot[w];
  unsigned int eqr = pre + c - cnt;
  unsigned int pk[2] = {0u, 0u};
#pragma unroll
  for (int j = 0; j < 8; ++j) {
    bool keep = u[j] > T;
    if (u[j] == T) { keep = (eqr < rkeep); eqr++; }
    float q = 0.0f;
    if (keep) {
      q = rintf(v[j] * s);
      q = fminf(fmaxf(q, -128.0f), 127.0f);
    }
    pk[j >> 2] |= ((unsigned int)(unsigned char)(signed char)q) << ((j & 3) * 8);
  }
  *(uint2*)(oq + (size_t)row * 2048 + tid * 8) = make_uint2(pk[0], pk[1]);
  if (tid == 0) so[row] = s;
}

// ---------------------------------------------------------------------------
extern "C" void kernel_launch(void* const* d_in, const int* in_sizes, int n_in,
                              void* d_out, int out_size, void* d_ws,
                              size_t ws_size, hipStream_t stream) {
  const float* x = (const float*)d_in[0];
  const float* wq = (const float*)d_in[1];
  const float* wk = (const float*)d_in[2];
  const float* wv = (const float*)d_in[3];
  const float* wo = (const float*)d_in[4];
  float* out = (float*)d_out;

  char* ws = (char*)d_ws;
  size_t off = 0;
  auto alloc = [&](size_t bytes) -> void* {
    void* p = ws + off;
    off += (bytes + 255) & ~(size_t)255;
    return p;
  };
  signed char* wt = (signed char*)alloc(4ull * 2048 * 2048);  // 16.8MB
  signed char* xq = (signed char*)alloc(4096ull * 2048);      // 8.4MB
  float* qb = (float*)alloc(4096ull * 2048 * 4);              // 33.5MB
  signed char* oq = (signed char*)alloc(4096ull * 2048);      // 8.4MB
  _Float16* kh = (_Float16*)alloc(32ull * 2048 * 128 * 2);   // 16.8MB
  _Float16* kl = (_Float16*)alloc(32ull * 2048 * 128 * 2);   // 16.8MB
  _Float16* vth = (_Float16*)alloc(32ull * 128 * 2048 * 2);  // 16.8MB
  _Float16* vtl = (_Float16*)alloc(32ull * 128 * 2048 * 2);  // 16.8MB
  float* ct = (float*)alloc(2048ull * 64 * 4);
  float* st = (float*)alloc(2048ull * 64 * 4);
  float* sx = (float*)alloc(4096 * 4);
  float* so = (float*)alloc(4096 * 4);
  float* wsc = (float*)alloc(4 * 4);
  double* prt = (double*)alloc(4096 * 8);

  k_costab<<<512, 256, 0, stream>>>(ct, st);
  k_wsum<<<4096, 256, 0, stream>>>(wq, wk, wv, wo, prt);
  k_wscale<<<4, 256, 0, stream>>>(prt, wsc);
  k_wquant<<<dim3(1024, 4), 256, 0, stream>>>(wq, wk, wv, wo, wsc, wt);
  k_xquant<<<4096, 256, 0, stream>>>(x, xq, sx);

  k_gemm3<<<dim3(48, 32), 256, 0, stream>>>(xq, wt, qb, kh, kl, vth, vtl, sx,
                                            wsc, ct, st);
  k_attn<<<512, 256, 0, stream>>>(qb, kh, kl, vth, vtl);  // O -> qb in-place
  k_topk<<<4096, 256, 0, stream>>>(qb, oq, so);
  k_gemm<<<dim3(16, 32), 256, 0, stream>>>(oq, wt + 3ull * 4194304, out, so,
                                           wsc + 3);
}